// Round 2
// baseline (23021.927 us; speedup 1.0000x reference)
//
#include <hip/hip_runtime.h>

// Persistent-grid DNC encoder for MI355X (gfx950).
// 128 blocks x 256 threads, ~112KB dynamic LDS/block -> 1 block/CU -> all
// blocks co-resident. Grid barrier = per-block arrival flags (parallel release
// stores, 64B apart) + master-block scan + single release flag (monotonic
// sequence numbers, no resets). 2 barriers per timestep.

constexpr int NBLK = 128;     // grid blocks
constexpr int BS   = 256;     // threads per block
constexpr int BQ   = 32;      // batch
constexpr int TT   = 256;     // time steps
constexpr int HH   = 512;     // hidden
constexpr int RH   = 4;       // read heads
constexpr int NC   = 64;      // cells
constexpr int XI   = 471;
constexpr int XIP  = 480;     // padded xi row stride (floats)
constexpr int KG   = 1280;    // gates K = 512(x)+256(r)+512(h)
constexpr int KGP  = 1288;    // padded LDS K stride (bf16)
constexpr int WOP  = 776;     // padded W_out K stride
constexpr int MASTER = NBLK - 1;
constexpr float CLIPV = 50000.0f;
constexpr float EPSV  = 1e-6f;

typedef __bf16 bf16x8 __attribute__((ext_vector_type(8)));
typedef float  f32x4  __attribute__((ext_vector_type(4)));

// ---- LDS layout (bytes) ----
constexpr int OFF_WG   = 0;                      // 16*KGP bf16 = 41216
constexpr int OFF_WO   = OFF_WG  + 16*KGP*2;     // 16*WOP bf16 = 24832
constexpr int OFF_GT   = OFF_WO  + 16*WOP*2;     // 32*17 f32   = 2176
constexpr int OFF_CST  = OFF_GT  + 32*17*4;      // 32*4 f32    = 512
constexpr int OFF_HL   = OFF_CST + 32*4*4;       // 512 f32     = 2048
constexpr int OFF_DNC  = OFF_HL  + 512*4;
constexpr int D_M    = 0;                        // 64*65 f32
constexpr int D_L    = D_M   + 64*65*4;
constexpr int D_XIR  = D_L   + 64*65*4;          // 480 f32
constexpr int D_WR   = D_XIR + XIP*4;            // 4*64
constexpr int D_FWD  = D_WR  + 256*4;
constexpr int D_BWD  = D_FWD + 256*4;
constexpr int D_SIMR = D_BWD + 256*4;
constexpr int D_VEC  = D_SIMR+ 256*4;            // 8 arrays of 64 f32
constexpr int D_SCAL = D_VEC + 8*64*4;           // 32 f32
constexpr int SMEM_BYTES = OFF_DNC + D_SCAL + 32*4;   // = 112256

// ---- workspace layout (bytes) ----
constexpr size_t WS_BARS = 0;                        // 128 flags*64B + rel line
constexpr size_t WS_HBUF = 8448;                     // 2*32*512 bf16 = 65536
constexpr size_t WS_RBUF = WS_HBUF + 65536;          // 32*256 bf16   = 16384
constexpr size_t WS_WXB  = WS_RBUF + 16384;          // 512*471 bf16  = 482304
constexpr size_t WS_EMB  = WS_WXB + 482304;          // 32*256*512 bf16 = 8388608
constexpr size_t WS_MIN  = WS_WXB + 482304;          // 572672
constexpr size_t WS_FULL = WS_EMB + 8388608;         // 8961280
constexpr size_t WS_ZERO = WS_RBUF + 16384;          // memset range: bars+h0+r0

__device__ __forceinline__ unsigned short f2b(float f) {
  unsigned u = __builtin_bit_cast(unsigned, f);
  u += 0x7fffu + ((u >> 16) & 1u);
  return (unsigned short)(u >> 16);
}
__device__ __forceinline__ float sigf(float x) { return 1.0f / (1.0f + expf(-x)); }
__device__ __forceinline__ float softplusf(float x) { return (x > 20.0f) ? x : log1pf(expf(x)); }
__device__ __forceinline__ float wsum(float v) {
  #pragma unroll
  for (int o = 32; o; o >>= 1) v += __shfl_xor(v, o, 64);
  return v;
}
__device__ __forceinline__ float wmaxr(float v) {
  #pragma unroll
  for (int o = 32; o; o >>= 1) v = fmaxf(v, __shfl_xor(v, o, 64));
  return v;
}
__device__ __forceinline__ f32x4 mfma16(bf16x8 a, bf16x8 b, f32x4 c) {
  return __builtin_amdgcn_mfma_f32_16x16x32_bf16(a, b, c, 0, 0, 0);
}

// Grid barrier: arrival flags at bars[blk*16] (64B apart), release at bars[NBLK*16].
// seq is monotonically increasing; flags never reset.
__device__ __forceinline__ void gbar(unsigned* bars, unsigned seq) {
  __syncthreads();   // drains each wave's vmcnt -> all block stores are in L2
  const int tid = threadIdx.x;
  unsigned* rel = bars + NBLK * 16;
  if (blockIdx.x == (unsigned)MASTER) {
    if (tid == 0)
      __hip_atomic_store(&bars[MASTER * 16], seq, __ATOMIC_RELEASE, __HIP_MEMORY_SCOPE_AGENT);
    if (tid < 64) {
      unsigned a0 = 0, a1 = 0;
      const int i0 = tid * 2, i1 = tid * 2 + 1;
      for (;;) {
        if (a0 < seq) a0 = __hip_atomic_load(&bars[i0 * 16], __ATOMIC_RELAXED, __HIP_MEMORY_SCOPE_AGENT);
        if (a1 < seq) a1 = __hip_atomic_load(&bars[i1 * 16], __ATOMIC_RELAXED, __HIP_MEMORY_SCOPE_AGENT);
        if (__all(a0 >= seq && a1 >= seq)) break;
        __builtin_amdgcn_s_sleep(1);
      }
      __builtin_amdgcn_fence(__ATOMIC_ACQUIRE, "agent");
      if (tid == 0)
        __hip_atomic_store(rel, seq, __ATOMIC_RELEASE, __HIP_MEMORY_SCOPE_AGENT);
    }
    __syncthreads();
  } else {
    if (tid == 0) {
      __hip_atomic_store(&bars[blockIdx.x * 16], seq, __ATOMIC_RELEASE, __HIP_MEMORY_SCOPE_AGENT);
      while (__hip_atomic_load(rel, __ATOMIC_RELAXED, __HIP_MEMORY_SCOPE_AGENT) < seq)
        __builtin_amdgcn_s_sleep(1);
      __builtin_amdgcn_fence(__ATOMIC_ACQUIRE, "agent");
    }
    __syncthreads();
  }
}

__global__ __launch_bounds__(BS, 1) void dnc_kernel(
    const int* __restrict__ src, const float* __restrict__ emb,
    const float* __restrict__ Wih, const float* __restrict__ Whh,
    const float* __restrict__ b_lstm, const float* __restrict__ W_xi,
    const float* __restrict__ b_xi, const float* __restrict__ W_out,
    const float* __restrict__ b_out, float* __restrict__ out,
    unsigned* __restrict__ bars, unsigned short* __restrict__ hbuf,
    unsigned short* __restrict__ rbuf, unsigned short* __restrict__ wxb_,
    unsigned short* __restrict__ embbuf_)
{
  extern __shared__ char smem[];
  __bf16* lWg  = (__bf16*)(smem + OFF_WG);
  __bf16* lWo  = (__bf16*)(smem + OFF_WO);
  float*  gt   = (float*)(smem + OFF_GT);
  float*  cst  = (float*)(smem + OFF_CST);
  float*  hl   = (float*)(smem + OFF_HL);
  char*   dnc  = smem + OFF_DNC;
  float* Ml   = (float*)(dnc + D_M);
  float* Ll   = (float*)(dnc + D_L);
  float* xir  = (float*)(dnc + D_XIR);
  float* wrl  = (float*)(dnc + D_WR);
  float* fwd  = (float*)(dnc + D_FWD);
  float* bwd  = (float*)(dnc + D_BWD);
  float* simr = (float*)(dnc + D_SIMR);
  float* uu   = (float*)(dnc + D_VEC);
  float* pp   = uu + 64;
  float* wwl  = uu + 128;
  float* aas  = uu + 192;
  float* nrmo = uu + 256;
  float* nrmn = uu + 320;
  float* simw = uu + 384;
  float* er   = uu + 448;
  float* scal = (float*)(dnc + D_SCAL);
  // scal: [0]beta_w [1]g_a [2]g_w [3]wknrm [4..7]beta_r [8..11]rkn [12..15]free [16..27]pi

  const int tid  = threadIdx.x;
  const int blk  = blockIdx.x;
  const int lane = tid & 63;
  const int wv   = tid >> 6;
  const int q    = lane >> 4;
  const int n16  = lane & 15;
  const int j0   = blk << 2;    // h slice: columns j0..j0+3
  const __bf16* wxb = (const __bf16*)wxb_;
  const __bf16* embbuf = (const __bf16*)embbuf_;

  // ---------------- prepass ----------------
  for (int e = tid; e < 16 * KG; e += BS) {
    int k = e >> 4, cc = e & 15;
    int gcol = ((cc >> 2) << 9) + j0 + (cc & 3);   // gate*512 + h-col
    float w = (k < 768) ? Wih[k * 2048 + gcol] : Whh[(k - 768) * 2048 + gcol];
    lWg[cc * KGP + k] = (__bf16)w;
  }
  if (blk >= 64 && blk < 96) {
    for (int e = tid; e < 16 * 768; e += BS) {
      int k = e >> 4, cc = e & 15;
      int col = ((blk - 64) << 4) + cc;
      lWo[cc * WOP + k] = (__bf16)W_out[k * HH + col];
    }
  }
  if (wxb_) {   // W_xi -> bf16 workspace copy
    for (int i = blk * BS + tid; i < HH * XI; i += NBLK * BS)
      ((__bf16*)wxb_)[i] = (__bf16)W_xi[i];
  }
  if (embbuf_) { // gather emb[src] -> bf16 workspace
    for (int row = blk; row < BQ * TT; row += NBLK) {
      const float* s = emb + (size_t)src[row] * HH;
      __bf16* d = (__bf16*)embbuf_ + (size_t)row * HH;
      for (int e = tid; e < HH; e += BS) d[e] = (__bf16)s[e];
    }
  }
  if (tid < 128) cst[tid] = 0.0f;
  if (blk < BQ) {
    for (int e = tid; e < 64 * 65; e += BS) { Ml[e] = 0.0f; Ll[e] = 0.0f; }
    if (tid < 64) { uu[tid] = 0.0f; pp[tid] = 0.0f; wwl[tid] = 0.0f; }
    wrl[tid] = 0.0f;
  }
  gbar(bars, 1u);

  // y-phase: computes y_{t-1}; valid for t in [1..TT]; runs on waves 2,3
  auto do_y = [&](int t) {
    const __bf16* hp = (const __bf16*)(hbuf + ((t + 1) & 1) * (BQ * HH));
    const __bf16* rp = (const __bf16*)rbuf;
    const int mt = wv - 2;
    const int bb = (mt << 4) + n16;
    f32x4 a0 = {0.f, 0.f, 0.f, 0.f}, a1 = {0.f, 0.f, 0.f, 0.f};
    #pragma unroll
    for (int ks = 0; ks < 24; ++ks) {
      const int kq = (ks << 5) + (q << 3);
      bf16x8 A = (ks < 16) ? *(const bf16x8*)(hp + bb * HH + kq)
                           : *(const bf16x8*)(rp + bb * (RH * NC) + (kq - 512));
      bf16x8 Bf = *(const bf16x8*)(lWo + n16 * WOP + kq);
      if (ks & 1) a1 = mfma16(A, Bf, a1); else a0 = mfma16(A, Bf, a0);
    }
    const int col = ((blk - 64) << 4) + n16;
    const float bias = b_out[col];
    #pragma unroll
    for (int j = 0; j < 4; ++j) {
      int row = (mt << 4) + (q << 2) + j;
      float y = a0[j] + a1[j] + bias;
      y = fminf(fmaxf(y, -CLIPV), CLIPV);
      out[(size_t)row * (TT * HH) + (size_t)(t - 1) * HH + col] = y;
    }
  };

  unsigned seq = 2u;
  for (int t = 0; t < TT; ++t) {
    const __bf16* hprev = (const __bf16*)(hbuf + ((t + 1) & 1) * (BQ * HH));
    unsigned short* hcur = hbuf + (t & 1) * (BQ * HH);

    // ---------------- phase A: gates (waves 0,1) + y_{t-1} (waves 2,3 on blocks 64..95)
    if (wv < 2) {
      const int bb = (wv << 4) + n16;
      const __bf16* rp = (const __bf16*)rbuf;
      const __bf16* eb = embbuf ? (embbuf + ((size_t)bb * TT + t) * HH) : nullptr;
      const float* ep = embbuf ? nullptr
                               : (emb + (size_t)src[bb * TT + t] * HH + (q << 3));
      f32x4 a0 = {0.f, 0.f, 0.f, 0.f}, a1 = {0.f, 0.f, 0.f, 0.f};
      #pragma unroll
      for (int ks = 0; ks < 40; ++ks) {
        const int kq = (ks << 5) + (q << 3);
        bf16x8 A;
        if (ks < 16) {
          if (eb) {
            A = *(const bf16x8*)(eb + kq);
          } else {
            const float* p = ep + (ks << 5);
            #pragma unroll
            for (int j = 0; j < 8; ++j) A[j] = (__bf16)p[j];
          }
        } else if (ks < 24) {
          A = *(const bf16x8*)(rp + bb * (RH * NC) + (kq - 512));
        } else {
          A = *(const bf16x8*)(hprev + bb * HH + (kq - 768));
        }
        bf16x8 Bf = *(const bf16x8*)(lWg + n16 * KGP + kq);
        if (ks & 1) a1 = mfma16(A, Bf, a1); else a0 = mfma16(A, Bf, a0);
      }
      const int gcol = ((n16 >> 2) << 9) + j0 + (n16 & 3);
      const float bias = b_lstm[gcol];
      #pragma unroll
      for (int j = 0; j < 4; ++j)
        gt[((wv << 4) + (q << 2) + j) * 17 + n16] = a0[j] + a1[j] + bias;
    } else if (blk >= 64 && blk < 96 && t > 0) {
      do_y(t);
    }
    __syncthreads();
    if (tid < 128) {           // LSTM state update for our 4 h-columns
      const int b = tid >> 2, i = tid & 3;
      float gi = gt[b * 17 + i],     gf = gt[b * 17 + 4 + i];
      float gg = gt[b * 17 + 8 + i], go = gt[b * 17 + 12 + i];
      float c = cst[tid];
      c = sigf(gf) * c + sigf(gi) * tanhf(gg);
      float h = sigf(go) * tanhf(c);
      cst[tid] = c;
      hcur[b * HH + j0 + i] = f2b(h);
    }
    gbar(bars, seq++);

    // ---------------- phase C: xi + DNC memory update, one block per batch element
    if (blk < BQ) {
      // h_t[blk,:] -> LDS f32
      for (int e = tid; e < HH; e += BS)
        hl[e] = (float)((const __bf16*)hcur)[blk * HH + e];
      __syncthreads();
      // xi[blk,:] = hl @ W_xi + b_xi  (each thread: cols tid, tid+256)
      {
        float acc0 = 0.f, acc1 = 0.f;
        const int c0 = tid, c1 = tid + 256;
        const bool has1 = (c1 < XI);
        if (wxb) {
          const __bf16* w0 = wxb + c0;
          #pragma unroll 8
          for (int k = 0; k < HH; ++k) {
            float hv = hl[k];
            acc0 += hv * (float)w0[k * XI];
            if (has1) acc1 += hv * (float)w0[k * XI + 256];
          }
        } else {
          const float* w0 = W_xi + c0;
          #pragma unroll 8
          for (int k = 0; k < HH; ++k) {
            float hv = hl[k];
            acc0 += hv * w0[k * XI];
            if (has1) acc1 += hv * w0[k * XI + 256];
          }
        }
        xir[c0] = acc0 + b_xi[c0];
        if (has1) xir[c1] = acc1 + b_xi[c1];
      }
      __syncthreads();
      if (tid == 0) {
        scal[0] = 1.0f + softplusf(xir[324]);   // beta_w
        scal[1] = sigf(xir[457]);               // g_a
        scal[2] = sigf(xir[458]);               // g_w
      }
      if (tid >= 4 && tid < 8) {
        int r = tid - 4;
        scal[4 + r]  = 1.0f + softplusf(xir[256 + r]);  // beta_r
        scal[12 + r] = sigf(xir[453 + r]);              // free
        float p0 = xir[459 + r * 3], p1 = xir[460 + r * 3], p2 = xir[461 + r * 3];
        float m = fmaxf(p0, fmaxf(p1, p2));
        float e0 = expf(p0 - m), e1 = expf(p1 - m), e2 = expf(p2 - m);
        float s = e0 + e1 + e2;
        scal[16 + r * 3 + 0] = e0 / s;
        scal[16 + r * 3 + 1] = e1 / s;
        scal[16 + r * 3 + 2] = e2 / s;
      }
      if (tid >= 64 && tid < 128) er[tid - 64] = sigf(xir[325 + (tid - 64)]);
      __syncthreads();
      // -- old norms / write-key sim / usage + stable sort + allocation
      if (wv == 0) {
        float s = 0.f;
        for (int w = 0; w < 64; ++w) { float m = Ml[lane * 65 + w]; s += m * m; }
        nrmo[lane] = sqrtf(s) + EPSV;
      } else if (wv == 1) {
        float d = 0.f;
        for (int w = 0; w < 64; ++w) d += Ml[lane * 65 + w] * xir[260 + w];
        simw[lane] = d;
        float v = xir[260 + lane];
        float s2 = wsum(v * v);
        if (lane == 0) scal[3] = sqrtf(s2) + EPSV;
      } else if (wv == 2) {
        float psi = 1.f;
        #pragma unroll
        for (int r = 0; r < 4; ++r) psi *= (1.f - scal[12 + r] * wrl[r * 64 + lane]);
        float un = uu[lane], w_ = wwl[lane];
        un = (un + w_ - un * w_) * psi;
        uu[lane] = un;
        // stable bitonic argsort ascending by (u, index)
        float v = un; int id = lane;
        for (int k = 2; k <= 64; k <<= 1) {
          for (int j2 = k >> 1; j2 > 0; j2 >>= 1) {
            float ov = __shfl_xor(v, j2, 64);
            int   oi = __shfl_xor(id, j2, 64);
            bool up    = ((lane & k) == 0);
            bool lower = ((lane & j2) == 0);
            bool lt = (v < ov) || (v == ov && id < oi);
            bool keep = (lower == up) ? lt : !lt;
            if (!keep) { v = ov; id = oi; }
          }
        }
        float cp = v;   // inclusive cumprod of sorted u
        for (int d2 = 1; d2 < 64; d2 <<= 1) {
          float o = __shfl_up(cp, d2, 64);
          if (lane >= d2) cp *= o;
        }
        float pe = __shfl_up(cp, 1, 64);
        if (lane == 0) pe = 1.0f;
        aas[id] = (1.0f - v) * pe;
      }
      __syncthreads();
      // -- write content weights -> ww
      if (wv == 0) {
        float x = simw[lane] / (nrmo[lane] * scal[3]) * scal[0];
        float mx = wmaxr(x);
        float e = expf(x - mx);
        float s = wsum(e);
        float cw = e / s;
        wwl[lane] = scal[2] * (scal[1] * aas[lane] + (1.f - scal[1]) * cw);
      }
      __syncthreads();
      // -- M and L updates (old p)
      {
        const int n = tid >> 2, c4 = (tid & 3) << 4;
        float wwn = wwl[n];
        #pragma unroll
        for (int w = 0; w < 16; ++w) {
          int wj = c4 + w;
          Ml[n * 65 + wj] = Ml[n * 65 + wj] * (1.f - wwn * er[wj]) + wwn * xir[389 + wj];
        }
        #pragma unroll
        for (int w = 0; w < 16; ++w) {
          int m2 = c4 + w;
          float Lv = (n == m2) ? 0.f
                   : ((1.f - wwn - wwl[m2]) * Ll[n * 65 + m2] + wwn * pp[m2]);
          Ll[n * 65 + m2] = Lv;
        }
      }
      __syncthreads();
      // -- fwd/bwd (old wr, new L), read-key sims (new M), new norms
      {
        float f = 0.f, bw2 = 0.f, d = 0.f;
        for (int m2 = 0; m2 < 64; ++m2) {
          float wrm = wrl[wv * 64 + m2];
          f   += Ll[lane * 65 + m2] * wrm;
          bw2 += Ll[m2 * 65 + lane] * wrm;
        }
        fwd[wv * 64 + lane] = f;
        bwd[wv * 64 + lane] = bw2;
        for (int w = 0; w < 64; ++w) d += Ml[lane * 65 + w] * xir[wv * 64 + w];
        simr[wv * 64 + lane] = d;
        float v = xir[wv * 64 + lane];
        float s2 = wsum(v * v);
        if (lane == 0) scal[8 + wv] = sqrtf(s2) + EPSV;
        if (wv == 0) {
          float s = 0.f;
          for (int w = 0; w < 64; ++w) { float m = Ml[lane * 65 + w]; s += m * m; }
          nrmn[lane] = sqrtf(s) + EPSV;
        }
      }
      __syncthreads();
      // -- read content weights, new wr, p update
      {
        float x = simr[wv * 64 + lane] / (nrmn[lane] * scal[8 + wv]) * scal[4 + wv];
        float mx = wmaxr(x);
        float e = expf(x - mx);
        float s = wsum(e);
        float cw = e / s;
        float wrn = scal[16 + wv * 3 + 0] * bwd[wv * 64 + lane]
                  + scal[16 + wv * 3 + 1] * cw
                  + scal[16 + wv * 3 + 2] * fwd[wv * 64 + lane];
        wrl[wv * 64 + lane] = wrn;
        if (wv == 3) {
          float s3 = wsum(wwl[lane]);
          pp[lane] = (1.f - s3) * pp[lane] + wwl[lane];
        }
      }
      __syncthreads();
      // -- r = wr @ M -> rbuf (bf16)
      {
        float rv = 0.f;
        for (int n2 = 0; n2 < 64; ++n2) rv += wrl[wv * 64 + n2] * Ml[n2 * 65 + lane];
        rbuf[blk * (RH * NC) + wv * 64 + lane] = f2b(rv);
      }
    }
    gbar(bars, seq++);
  }

  // final y_{T-1}
  if (blk >= 64 && blk < 96 && wv >= 2) do_y(TT);
}

extern "C" void kernel_launch(void* const* d_in, const int* in_sizes, int n_in,
                              void* d_out, int out_size, void* d_ws, size_t ws_size,
                              hipStream_t stream) {
  const int*   src    = (const int*)d_in[0];
  // d_in[1] = source_lengths (unused)
  const float* emb    = (const float*)d_in[2];
  const float* Wih    = (const float*)d_in[3];
  const float* Whh    = (const float*)d_in[4];
  const float* b_lstm = (const float*)d_in[5];
  const float* W_xi   = (const float*)d_in[6];
  const float* b_xi   = (const float*)d_in[7];
  const float* W_out  = (const float*)d_in[8];
  const float* b_out  = (const float*)d_in[9];
  float* out = (float*)d_out;

  char* ws = (char*)d_ws;
  unsigned*       bars   = (unsigned*)(ws + WS_BARS);
  unsigned short* hbuf   = (unsigned short*)(ws + WS_HBUF);
  unsigned short* rbuf   = (unsigned short*)(ws + WS_RBUF);
  unsigned short* wxb    = (ws_size >= WS_MIN)  ? (unsigned short*)(ws + WS_WXB) : nullptr;
  unsigned short* embbuf = (ws_size >= WS_FULL) ? (unsigned short*)(ws + WS_EMB) : nullptr;

  hipMemsetAsync(d_ws, 0, WS_ZERO, stream);   // barrier flags + h0 + r0 zeros
  hipFuncSetAttribute((const void*)dnc_kernel,
                      hipFuncAttributeMaxDynamicSharedMemorySize, SMEM_BYTES);
  dnc_kernel<<<dim3(NBLK), dim3(BS), SMEM_BYTES, stream>>>(
      src, emb, Wih, Whh, b_lstm, W_xi, b_xi, W_out, b_out, out,
      bars, hbuf, rbuf, wxb, embbuf);
}

// Round 3
// 12848.982 us; speedup vs baseline: 1.7917x; 1.7917x over previous
//
#include <hip/hip_runtime.h>

// Persistent-grid DNC encoder for MI355X (gfx950).
// 128 blocks x 256 threads, ~113KB LDS/block -> 1 block/CU -> co-resident.
// Grid barrier: per-block arrival flags (64B apart) + master scan + release
// flag. All cross-block DATA moves via relaxed agent-scope atomics
// (write-through to MALL / MALL-direct loads) -> no acquire fences, no
// buffer_inv, L2 stays warm (W_xi^T copy, embeddings). 2 barriers/step.

constexpr int NBLK = 128;
constexpr int BS   = 256;
constexpr int BQ   = 32;
constexpr int TT   = 256;
constexpr int HH   = 512;
constexpr int RH   = 4;
constexpr int NC   = 64;
constexpr int XI   = 471;
constexpr int KG   = 1280;    // gates K = 512(x)+256(r)+512(h)
constexpr int KGP  = 1288;    // padded LDS K stride (bf16)
constexpr int WOP  = 776;     // padded W_out K stride
constexpr int MASTER = NBLK - 1;
constexpr float CLIPV = 50000.0f;
constexpr float EPSV  = 1e-6f;

typedef __bf16 bf16x8 __attribute__((ext_vector_type(8)));
typedef float  f32x4  __attribute__((ext_vector_type(4)));
typedef unsigned long long u64;

// ---- LDS layout (bytes) ----
constexpr int OFF_WG   = 0;                      // 16*KGP bf16 = 41216
constexpr int OFF_WO   = OFF_WG  + 16*KGP*2;     // 16*WOP bf16 = 24832
constexpr int OFF_GT   = OFF_WO  + 16*WOP*2;     // 32*17 f32   = 2176
constexpr int OFF_CST  = OFF_GT  + 32*17*4;      // 128 f32     = 512
constexpr int OFF_HL   = OFF_CST + 512;          // 512 f32     = 2048
constexpr int OFF_HLB  = OFF_HL  + 2048;         // 512 bf16    = 1024
constexpr int OFF_DNC  = OFF_HLB + 1024;
constexpr int D_M    = 0;                        // 64*65 f32
constexpr int D_L    = D_M   + 64*65*4;
constexpr int D_XIR  = D_L   + 64*65*4;          // 480 f32
constexpr int D_WR   = D_XIR + 480*4;
constexpr int D_FWD  = D_WR  + 256*4;
constexpr int D_BWD  = D_FWD + 256*4;
constexpr int D_SIMR = D_BWD + 256*4;
constexpr int D_VEC  = D_SIMR+ 256*4;            // 8 arrays of 64 f32
constexpr int D_SCAL = D_VEC + 8*64*4;           // 32 f32
constexpr int SMEM_BYTES = OFF_DNC + D_SCAL + 32*4;   // 113280

// ---- workspace layout (bytes) ----
constexpr size_t WS_BARS = 0;                          // flags: 128*64 + rel
constexpr size_t WS_HBUF = 8448;                       // 2*32*512 bf16 = 65536
constexpr size_t WS_RBUF = WS_HBUF + 65536;            // 32*256 bf16   = 16384
constexpr size_t WS_WXBT = WS_RBUF + 16384;            // 480*512 bf16  = 491520
constexpr size_t WS_EMB  = WS_WXBT + 491520;           // 8192*512 bf16 = 8388608
constexpr size_t WS_MIN  = WS_WXBT + 491520;           // 581888
constexpr size_t WS_FULL = WS_EMB + 8388608;           // 8970496
constexpr size_t WS_ZERO = WS_RBUF + 16384;            // bars + h0 + r0

__device__ __forceinline__ unsigned short f2b(float f) {
  unsigned u = __builtin_bit_cast(unsigned, f);
  u += 0x7fffu + ((u >> 16) & 1u);
  return (unsigned short)(u >> 16);
}
__device__ __forceinline__ float b2f(unsigned short us) {
  return __builtin_bit_cast(float, ((unsigned)us) << 16);
}
__device__ __forceinline__ float sigf(float x) { return 1.0f / (1.0f + expf(-x)); }
__device__ __forceinline__ float softplusf(float x) { return (x > 20.0f) ? x : log1pf(expf(x)); }
__device__ __forceinline__ float wsum(float v) {
  #pragma unroll
  for (int o = 32; o; o >>= 1) v += __shfl_xor(v, o, 64);
  return v;
}
__device__ __forceinline__ float wmaxr(float v) {
  #pragma unroll
  for (int o = 32; o; o >>= 1) v = fmaxf(v, __shfl_xor(v, o, 64));
  return v;
}
__device__ __forceinline__ f32x4 mfma16(bf16x8 a, bf16x8 b, f32x4 c) {
  return __builtin_amdgcn_mfma_f32_16x16x32_bf16(a, b, c, 0, 0, 0);
}

// MALL write-through / MALL-direct data movement (relaxed agent atomics)
__device__ __forceinline__ void st_u64(u64* p, u64 v) {
  __hip_atomic_store(p, v, __ATOMIC_RELAXED, __HIP_MEMORY_SCOPE_AGENT);
}
__device__ __forceinline__ u64 ld_u64(const u64* p) {
  return __hip_atomic_load(p, __ATOMIC_RELAXED, __HIP_MEMORY_SCOPE_AGENT);
}
struct alignas(16) U64x2 { u64 a, b; };
__device__ __forceinline__ bf16x8 ld_bf16x8_mall(const unsigned short* p) {
  U64x2 v;
  v.a = ld_u64((const u64*)p);
  v.b = ld_u64((const u64*)p + 1);
  return __builtin_bit_cast(bf16x8, v);
}

// Grid barrier: parallel arrival flags, master scan, single release flag.
// Monotonic seq, flags never reset. No acquire fences (data is MALL-direct).
__device__ __forceinline__ void gbar(unsigned* bars, unsigned seq) {
  __syncthreads();   // compiler drains vmcnt before s_barrier -> data at MALL
  const int tid = threadIdx.x;
  unsigned* rel = bars + NBLK * 16;
  if (blockIdx.x == (unsigned)MASTER) {
    if (tid == 0)
      __hip_atomic_store(&bars[MASTER * 16], seq, __ATOMIC_RELEASE, __HIP_MEMORY_SCOPE_AGENT);
    if (tid < 64) {
      unsigned a0 = 0, a1 = 0;
      const int i0 = tid * 2, i1 = tid * 2 + 1;
      for (;;) {
        if (a0 < seq) a0 = __hip_atomic_load(&bars[i0 * 16], __ATOMIC_RELAXED, __HIP_MEMORY_SCOPE_AGENT);
        if (a1 < seq) a1 = __hip_atomic_load(&bars[i1 * 16], __ATOMIC_RELAXED, __HIP_MEMORY_SCOPE_AGENT);
        if (__all(a0 >= seq && a1 >= seq)) break;
        __builtin_amdgcn_s_sleep(1);
      }
      if (tid == 0)
        __hip_atomic_store(rel, seq, __ATOMIC_RELEASE, __HIP_MEMORY_SCOPE_AGENT);
    }
  } else {
    if (tid == 0) {
      __hip_atomic_store(&bars[blockIdx.x * 16], seq, __ATOMIC_RELEASE, __HIP_MEMORY_SCOPE_AGENT);
      while (__hip_atomic_load(rel, __ATOMIC_RELAXED, __HIP_MEMORY_SCOPE_AGENT) < seq)
        __builtin_amdgcn_s_sleep(1);
    }
  }
  __builtin_amdgcn_fence(__ATOMIC_ACQUIRE, "workgroup");  // compile-order only
  __syncthreads();
}

__global__ __launch_bounds__(BS, 1) void dnc_kernel(
    const int* __restrict__ src, const float* __restrict__ emb,
    const float* __restrict__ Wih, const float* __restrict__ Whh,
    const float* __restrict__ b_lstm, const float* __restrict__ W_xi,
    const float* __restrict__ b_xi, const float* __restrict__ W_out,
    const float* __restrict__ b_out, float* __restrict__ out,
    unsigned* __restrict__ bars, unsigned short* __restrict__ hbuf,
    unsigned short* __restrict__ rbuf, unsigned short* __restrict__ wxbT_,
    unsigned short* __restrict__ embbuf_)
{
  extern __shared__ char smem[];
  __bf16* lWg  = (__bf16*)(smem + OFF_WG);
  __bf16* lWo  = (__bf16*)(smem + OFF_WO);
  float*  gt   = (float*)(smem + OFF_GT);
  float*  cst  = (float*)(smem + OFF_CST);
  float*  hl   = (float*)(smem + OFF_HL);
  __bf16* hlb  = (__bf16*)(smem + OFF_HLB);
  char*   dnc  = smem + OFF_DNC;
  float* Ml   = (float*)(dnc + D_M);
  float* Ll   = (float*)(dnc + D_L);
  float* xir  = (float*)(dnc + D_XIR);
  float* wrl  = (float*)(dnc + D_WR);
  float* fwd  = (float*)(dnc + D_FWD);
  float* bwd  = (float*)(dnc + D_BWD);
  float* simr = (float*)(dnc + D_SIMR);
  float* uu   = (float*)(dnc + D_VEC);
  float* pp   = uu + 64;
  float* wwl  = uu + 128;
  float* aas  = uu + 192;
  float* nrmo = uu + 256;
  float* nrmn = uu + 320;
  float* simw = uu + 384;
  float* er   = uu + 448;
  float* scal = (float*)(dnc + D_SCAL);
  // scal: [0]beta_w [1]g_a [2]g_w [3]wknrm [4..7]beta_r [8..11]rkn [12..15]free [16..27]pi

  const int tid  = threadIdx.x;
  const int blk  = blockIdx.x;
  const int lane = tid & 63;
  const int wv   = tid >> 6;
  const int q    = lane >> 4;
  const int n16  = lane & 15;
  const int j0   = blk << 2;    // h slice: columns j0..j0+3
  const __bf16* wxbT = (const __bf16*)wxbT_;
  const __bf16* embbuf = (const __bf16*)embbuf_;

  // ---------------- prepass ----------------
  for (int e = tid; e < 16 * KG; e += BS) {
    int k = e >> 4, cc = e & 15;
    int gcol = ((cc >> 2) << 9) + j0 + (cc & 3);   // gate*512 + h-col
    float w = (k < 768) ? Wih[k * 2048 + gcol] : Whh[(k - 768) * 2048 + gcol];
    lWg[cc * KGP + k] = (__bf16)w;
  }
  if (blk >= 64 && blk < 96) {
    for (int e = tid; e < 16 * 768; e += BS) {
      int k = e >> 4, cc = e & 15;
      int col = ((blk - 64) << 4) + cc;
      lWo[cc * WOP + k] = (__bf16)W_out[k * HH + col];
    }
  }
  if (wxbT_) {   // W_xi^T -> bf16 [col][k] workspace (write-through)
    for (int f = blk * BS + tid; f < XI * 128; f += NBLK * BS) {
      int col = f >> 7, k4 = (f & 127) << 2;
      u64 pk = 0;
      #pragma unroll
      for (int j = 0; j < 4; ++j) {
        unsigned short us = f2b(W_xi[(size_t)(k4 + j) * XI + col]);
        pk |= (u64)us << (16 * j);
      }
      st_u64((u64*)(wxbT_ + (size_t)col * 512 + k4), pk);
    }
  }
  if (embbuf_) { // gather emb[src] -> bf16 workspace (write-through)
    for (int rr = blk * 2 + (tid >> 7); rr < BQ * TT; rr += NBLK * 2) {
      const int t128 = tid & 127;
      const float* s = emb + (size_t)src[rr] * HH;
      float4 v = *(const float4*)(s + t128 * 4);
      u64 pk = (u64)f2b(v.x) | ((u64)f2b(v.y) << 16)
             | ((u64)f2b(v.z) << 32) | ((u64)f2b(v.w) << 48);
      st_u64((u64*)(embbuf_ + (size_t)rr * HH + t128 * 4), pk);
    }
  }
  if (tid < 128) cst[tid] = 0.0f;
  if (blk < BQ) {
    for (int e = tid; e < 64 * 65; e += BS) { Ml[e] = 0.0f; Ll[e] = 0.0f; }
    if (tid < 64) { uu[tid] = 0.0f; pp[tid] = 0.0f; wwl[tid] = 0.0f; }
    wrl[tid] = 0.0f;
  }
  gbar(bars, 1u);

  // y-phase: computes y_{t-1}; valid t in [1..TT]; runs on waves 2,3
  auto do_y = [&](int t) {
    const unsigned short* hp = hbuf + ((t + 1) & 1) * (BQ * HH);
    const int mt = wv - 2;
    const int bb = (mt << 4) + n16;
    f32x4 a0 = {0.f, 0.f, 0.f, 0.f}, a1 = {0.f, 0.f, 0.f, 0.f};
    #pragma unroll
    for (int ks = 0; ks < 24; ++ks) {
      const int kq = (ks << 5) + (q << 3);
      bf16x8 A = (ks < 16) ? ld_bf16x8_mall(hp + bb * HH + kq)
                           : ld_bf16x8_mall(rbuf + bb * (RH * NC) + (kq - 512));
      bf16x8 Bf = *(const bf16x8*)(lWo + n16 * WOP + kq);
      if (ks & 1) a1 = mfma16(A, Bf, a1); else a0 = mfma16(A, Bf, a0);
    }
    const int col = ((blk - 64) << 4) + n16;
    const float bias = b_out[col];
    #pragma unroll
    for (int j = 0; j < 4; ++j) {
      int row = (mt << 4) + (q << 2) + j;
      float y = a0[j] + a1[j] + bias;
      y = fminf(fmaxf(y, -CLIPV), CLIPV);
      out[(size_t)row * (TT * HH) + (size_t)(t - 1) * HH + col] = y;
    }
  };

  unsigned seq = 2u;
  for (int t = 0; t < TT; ++t) {
    const unsigned short* hprev = hbuf + ((t + 1) & 1) * (BQ * HH);
    unsigned short* hcur = hbuf + (t & 1) * (BQ * HH);

    // ---------------- phase A: gates (waves 0,1) + y_{t-1} (waves 2,3, blocks 64..95)
    if (wv < 2) {
      const int bb = (wv << 4) + n16;
      const __bf16* eb = embbuf ? (embbuf + ((size_t)bb * TT + t) * HH) : nullptr;
      const float* ep = embbuf ? nullptr
                               : (emb + (size_t)src[bb * TT + t] * HH + (q << 3));
      f32x4 a0 = {0.f, 0.f, 0.f, 0.f}, a1 = {0.f, 0.f, 0.f, 0.f};
      #pragma unroll
      for (int ks = 0; ks < 40; ++ks) {
        const int kq = (ks << 5) + (q << 3);
        bf16x8 A;
        if (ks < 16) {
          if (eb) {
            A = *(const bf16x8*)(eb + kq);   // plain: L2-warm, read-only
          } else {
            const float* p = ep + (ks << 5);
            #pragma unroll
            for (int j = 0; j < 8; ++j) A[j] = (__bf16)p[j];
          }
        } else if (ks < 24) {
          A = ld_bf16x8_mall(rbuf + bb * (RH * NC) + (kq - 512));
        } else {
          A = ld_bf16x8_mall(hprev + bb * HH + (kq - 768));
        }
        bf16x8 Bf = *(const bf16x8*)(lWg + n16 * KGP + kq);
        if (ks & 1) a1 = mfma16(A, Bf, a1); else a0 = mfma16(A, Bf, a0);
      }
      const int gcol = ((n16 >> 2) << 9) + j0 + (n16 & 3);
      const float bias = b_lstm[gcol];
      #pragma unroll
      for (int j = 0; j < 4; ++j)
        gt[((wv << 4) + (q << 2) + j) * 17 + n16] = a0[j] + a1[j] + bias;
    } else if (blk >= 64 && blk < 96 && t > 0) {
      do_y(t);
    }
    __syncthreads();
    if (tid < BQ) {            // LSTM update: batch=tid, our 4 h-columns, one u64 store
      const int b = tid;
      u64 hv = 0;
      #pragma unroll
      for (int i = 0; i < 4; ++i) {
        float gi = gt[(b * 4 + i) * 0 + b * 17 + i]; // placeholder avoided below
        (void)gi;
      }
      #pragma unroll
      for (int i = 0; i < 4; ++i) {
        float g_i = gt[b * 17 + i],     g_f = gt[b * 17 + 4 + i];
        float g_g = gt[b * 17 + 8 + i], g_o = gt[b * 17 + 12 + i];
        float c = cst[b * 4 + i];
        c = sigf(g_f) * c + sigf(g_i) * tanhf(g_g);
        float h = sigf(g_o) * tanhf(c);
        cst[b * 4 + i] = c;
        hv |= (u64)f2b(h) << (16 * i);
      }
      st_u64((u64*)(hcur + b * HH + j0), hv);
    }
    gbar(bars, seq++);

    // ---------------- phase C: xi (MFMA) + DNC update, one block per batch
    if (blk < BQ) {
      if (tid < 128) {         // h_t[blk,:] -> LDS (f32 + bf16)
        u64 hv = ld_u64((const u64*)(hcur + blk * HH + tid * 4));
        #pragma unroll
        for (int i = 0; i < 4; ++i) {
          unsigned short us = (unsigned short)(hv >> (16 * i));
          hl[tid * 4 + i]  = b2f(us);
          hlb[tid * 4 + i] = __builtin_bit_cast(__bf16, us);
        }
      }
      __syncthreads();
      // xi = h @ W_xi + b_xi via MFMA: wave wv owns col-tiles ct0..ct0+7 (<30)
      {
        constexpr int TPW = 8;
        f32x4 acc[TPW];
        #pragma unroll
        for (int i = 0; i < TPW; ++i) acc[i] = f32x4{0.f, 0.f, 0.f, 0.f};
        const int ct0 = wv * TPW;
        const int ntile = (ct0 + TPW <= 30) ? TPW : (30 - ct0);
        for (int kt = 0; kt < 16; ++kt) {
          bf16x8 Bf;
          #pragma unroll
          for (int j = 0; j < 8; ++j)
            Bf[j] = (n16 == 0) ? hlb[kt * 32 + (q << 3) + j] : (__bf16)0.0f;
          if (wxbT) {
            #pragma unroll
            for (int i = 0; i < TPW; ++i) {
              if (i < ntile) {
                const __bf16* ap = wxbT + (size_t)((ct0 + i) * 16 + n16) * 512
                                        + kt * 32 + (q << 3);
                acc[i] = mfma16(*(const bf16x8*)ap, Bf, acc[i]);
              }
            }
          } else {
            #pragma unroll
            for (int i = 0; i < TPW; ++i) {
              if (i < ntile) {
                const int col = (ct0 + i) * 16 + n16;
                bf16x8 Af;
                #pragma unroll
                for (int j = 0; j < 8; ++j)
                  Af[j] = (col < XI) ? (__bf16)W_xi[(size_t)(kt * 32 + (q << 3) + j) * XI + col]
                                     : (__bf16)0.0f;
                acc[i] = mfma16(Af, Bf, acc[i]);
              }
            }
          }
        }
        if (n16 == 0) {
          const int rowb = (lane >> 4) * 4;
          #pragma unroll
          for (int i = 0; i < TPW; ++i) {
            if (i < ntile) {
              #pragma unroll
              for (int j = 0; j < 4; ++j) {
                int col = (ct0 + i) * 16 + rowb + j;
                if (col < XI) xir[col] = acc[i][j] + b_xi[col];
              }
            }
          }
        }
      }
      __syncthreads();
      if (tid == 0) {
        scal[0] = 1.0f + softplusf(xir[324]);   // beta_w
        scal[1] = sigf(xir[457]);               // g_a
        scal[2] = sigf(xir[458]);               // g_w
      }
      if (tid >= 4 && tid < 8) {
        int r = tid - 4;
        scal[4 + r]  = 1.0f + softplusf(xir[256 + r]);  // beta_r
        scal[12 + r] = sigf(xir[453 + r]);              // free
        float p0 = xir[459 + r * 3], p1 = xir[460 + r * 3], p2 = xir[461 + r * 3];
        float m = fmaxf(p0, fmaxf(p1, p2));
        float e0 = expf(p0 - m), e1 = expf(p1 - m), e2 = expf(p2 - m);
        float s = e0 + e1 + e2;
        scal[16 + r * 3 + 0] = e0 / s;
        scal[16 + r * 3 + 1] = e1 / s;
        scal[16 + r * 3 + 2] = e2 / s;
      }
      if (tid >= 64 && tid < 128) er[tid - 64] = sigf(xir[325 + (tid - 64)]);
      __syncthreads();
      // -- old norms / write-key sim / usage + stable sort + allocation
      if (wv == 0) {
        float s = 0.f;
        for (int w = 0; w < 64; ++w) { float m = Ml[lane * 65 + w]; s += m * m; }
        nrmo[lane] = sqrtf(s) + EPSV;
      } else if (wv == 1) {
        float d = 0.f;
        for (int w = 0; w < 64; ++w) d += Ml[lane * 65 + w] * xir[260 + w];
        simw[lane] = d;
        float v = xir[260 + lane];
        float s2 = wsum(v * v);
        if (lane == 0) scal[3] = sqrtf(s2) + EPSV;
      } else if (wv == 2) {
        float psi = 1.f;
        #pragma unroll
        for (int r = 0; r < 4; ++r) psi *= (1.f - scal[12 + r] * wrl[r * 64 + lane]);
        float un = uu[lane], w_ = wwl[lane];
        un = (un + w_ - un * w_) * psi;
        uu[lane] = un;
        // stable bitonic argsort ascending by (u, index)
        float v = un; int id = lane;
        for (int k = 2; k <= 64; k <<= 1) {
          for (int j2 = k >> 1; j2 > 0; j2 >>= 1) {
            float ov = __shfl_xor(v, j2, 64);
            int   oi = __shfl_xor(id, j2, 64);
            bool up    = ((lane & k) == 0);
            bool lower = ((lane & j2) == 0);
            bool lt = (v < ov) || (v == ov && id < oi);
            bool keep = (lower == up) ? lt : !lt;
            if (!keep) { v = ov; id = oi; }
          }
        }
        float cp = v;
        for (int d2 = 1; d2 < 64; d2 <<= 1) {
          float o = __shfl_up(cp, d2, 64);
          if (lane >= d2) cp *= o;
        }
        float pe = __shfl_up(cp, 1, 64);
        if (lane == 0) pe = 1.0f;
        aas[id] = (1.0f - v) * pe;
      }
      __syncthreads();
      // -- write content weights -> ww
      if (wv == 0) {
        float x = simw[lane] / (nrmo[lane] * scal[3]) * scal[0];
        float mx = wmaxr(x);
        float e = expf(x - mx);
        float s = wsum(e);
        float cw = e / s;
        wwl[lane] = scal[2] * (scal[1] * aas[lane] + (1.f - scal[1]) * cw);
      }
      __syncthreads();
      // -- M and L updates (old p)
      {
        const int n = tid >> 2, c4 = (tid & 3) << 4;
        float wwn = wwl[n];
        #pragma unroll
        for (int w = 0; w < 16; ++w) {
          int wj = c4 + w;
          Ml[n * 65 + wj] = Ml[n * 65 + wj] * (1.f - wwn * er[wj]) + wwn * xir[389 + wj];
        }
        #pragma unroll
        for (int w = 0; w < 16; ++w) {
          int m2 = c4 + w;
          float Lv = (n == m2) ? 0.f
                   : ((1.f - wwn - wwl[m2]) * Ll[n * 65 + m2] + wwn * pp[m2]);
          Ll[n * 65 + m2] = Lv;
        }
      }
      __syncthreads();
      // -- fwd/bwd (old wr, new L), read-key sims (new M), new norms
      {
        float f = 0.f, bw2 = 0.f, d = 0.f;
        for (int m2 = 0; m2 < 64; ++m2) {
          float wrm = wrl[wv * 64 + m2];
          f   += Ll[lane * 65 + m2] * wrm;
          bw2 += Ll[m2 * 65 + lane] * wrm;
        }
        fwd[wv * 64 + lane] = f;
        bwd[wv * 64 + lane] = bw2;
        for (int w = 0; w < 64; ++w) d += Ml[lane * 65 + w] * xir[wv * 64 + w];
        simr[wv * 64 + lane] = d;
        float v = xir[wv * 64 + lane];
        float s2 = wsum(v * v);
        if (lane == 0) scal[8 + wv] = sqrtf(s2) + EPSV;
        if (wv == 0) {
          float s = 0.f;
          for (int w = 0; w < 64; ++w) { float m = Ml[lane * 65 + w]; s += m * m; }
          nrmn[lane] = sqrtf(s) + EPSV;
        }
      }
      __syncthreads();
      // -- read content weights, new wr, p update
      {
        float x = simr[wv * 64 + lane] / (nrmn[lane] * scal[8 + wv]) * scal[4 + wv];
        float mx = wmaxr(x);
        float e = expf(x - mx);
        float s = wsum(e);
        float cw = e / s;
        float wrn = scal[16 + wv * 3 + 0] * bwd[wv * 64 + lane]
                  + scal[16 + wv * 3 + 1] * cw
                  + scal[16 + wv * 3 + 2] * fwd[wv * 64 + lane];
        wrl[wv * 64 + lane] = wrn;
        if (wv == 3) {
          float s3 = wsum(wwl[lane]);
          pp[lane] = (1.f - s3) * pp[lane] + wwl[lane];
        }
      }
      __syncthreads();
      // -- r = wr @ M -> rbuf (bf16, packed u64 write-through)
      {
        float rv = 0.f;
        for (int n2 = 0; n2 < 64; ++n2) rv += wrl[wv * 64 + n2] * Ml[n2 * 65 + lane];
        unsigned v0 = f2b(rv);
        unsigned v1 = __shfl_down(v0, 1, 64);
        unsigned v2 = __shfl_down(v0, 2, 64);
        unsigned v3 = __shfl_down(v0, 3, 64);
        if ((lane & 3) == 0) {
          u64 pk = (u64)v0 | ((u64)v1 << 16) | ((u64)v2 << 32) | ((u64)v3 << 48);
          st_u64((u64*)(rbuf + blk * (RH * NC) + wv * 64 + lane), pk);
        }
      }
    }
    gbar(bars, seq++);
  }

  // final y_{T-1}
  if (blk >= 64 && blk < 96 && wv >= 2) do_y(TT);
}

extern "C" void kernel_launch(void* const* d_in, const int* in_sizes, int n_in,
                              void* d_out, int out_size, void* d_ws, size_t ws_size,
                              hipStream_t stream) {
  const int*   src    = (const int*)d_in[0];
  const float* emb    = (const float*)d_in[2];
  const float* Wih    = (const float*)d_in[3];
  const float* Whh    = (const float*)d_in[4];
  const float* b_lstm = (const float*)d_in[5];
  const float* W_xi   = (const float*)d_in[6];
  const float* b_xi   = (const float*)d_in[7];
  const float* W_out  = (const float*)d_in[8];
  const float* b_out  = (const float*)d_in[9];
  float* out = (float*)d_out;

  char* ws = (char*)d_ws;
  unsigned*       bars   = (unsigned*)(ws + WS_BARS);
  unsigned short* hbuf   = (unsigned short*)(ws + WS_HBUF);
  unsigned short* rbuf   = (unsigned short*)(ws + WS_RBUF);
  unsigned short* wxbT   = (ws_size >= WS_MIN)  ? (unsigned short*)(ws + WS_WXBT) : nullptr;
  unsigned short* embbuf = (ws_size >= WS_FULL) ? (unsigned short*)(ws + WS_EMB)  : nullptr;

  hipMemsetAsync(d_ws, 0, WS_ZERO, stream);   // barrier flags + h0 + r0
  hipFuncSetAttribute((const void*)dnc_kernel,
                      hipFuncAttributeMaxDynamicSharedMemorySize, SMEM_BYTES);
  dnc_kernel<<<dim3(NBLK), dim3(BS), SMEM_BYTES, stream>>>(
      src, emb, Wih, Whh, b_lstm, W_xi, b_xi, W_out, b_out, out,
      bars, hbuf, rbuf, wxbT, embbuf);
}

// Round 4
// 12327.509 us; speedup vs baseline: 1.8675x; 1.0423x over previous
//
#include <hip/hip_runtime.h>

// Persistent-grid DNC encoder for MI355X (gfx950).
// 128 blocks x 256 threads, ~113KB LDS/block -> 1 block/CU -> co-resident.
// Grid barrier: per-block arrival flags (64B apart) + master scan + release
// flag -- ALL RELAXED atomics (no buffer_wbl2 / buffer_inv in steady state).
// Safety: gbar opens with __syncthreads() whose codegen drains vmcnt(0); all
// cross-block data stores are MALL write-through atomics, so they are
// coherence-point-visible before any flag store. Mutable cross-block data
// (h, r) is read MALL-direct; write-once data (embbuf, wxbT) via plain loads.

constexpr int NBLK = 128;
constexpr int BS   = 256;
constexpr int BQ   = 32;
constexpr int TT   = 256;
constexpr int HH   = 512;
constexpr int RH   = 4;
constexpr int NC   = 64;
constexpr int XI   = 471;
constexpr int KG   = 1280;    // gates K = 512(x)+256(r)+512(h)
constexpr int KGP  = 1288;    // padded LDS K stride (bf16)
constexpr int WOP  = 776;     // padded W_out K stride
constexpr int MASTER = NBLK - 1;
constexpr float CLIPV = 50000.0f;
constexpr float EPSV  = 1e-6f;

typedef __bf16 bf16x8 __attribute__((ext_vector_type(8)));
typedef float  f32x4  __attribute__((ext_vector_type(4)));
typedef unsigned long long u64;

// ---- LDS layout (bytes) ----
constexpr int OFF_WG   = 0;                      // 16*KGP bf16 = 41216
constexpr int OFF_WO   = OFF_WG  + 16*KGP*2;     // 16*WOP bf16 = 24832
constexpr int OFF_GT   = OFF_WO  + 16*WOP*2;     // 32*17 f32   = 2176
constexpr int OFF_CST  = OFF_GT  + 32*17*4;      // 128 f32     = 512
constexpr int OFF_HL   = OFF_CST + 512;          // 512 f32     = 2048
constexpr int OFF_HLB  = OFF_HL  + 2048;         // 512 bf16    = 1024
constexpr int OFF_DNC  = OFF_HLB + 1024;
constexpr int D_M    = 0;                        // 64*65 f32
constexpr int D_L    = D_M   + 64*65*4;
constexpr int D_XIR  = D_L   + 64*65*4;          // 480 f32
constexpr int D_WR   = D_XIR + 480*4;
constexpr int D_FWD  = D_WR  + 256*4;
constexpr int D_BWD  = D_FWD + 256*4;
constexpr int D_SIMR = D_BWD + 256*4;
constexpr int D_VEC  = D_SIMR+ 256*4;            // 8 arrays of 64 f32
constexpr int D_SCAL = D_VEC + 8*64*4;           // 32 f32
constexpr int SMEM_BYTES = OFF_DNC + D_SCAL + 32*4;   // 113280

// ---- workspace layout (bytes) ----
constexpr size_t WS_BARS = 0;                          // flags: 128*64 + rel
constexpr size_t WS_HBUF = 8448;                       // 2*32*512 bf16 = 65536
constexpr size_t WS_RBUF = WS_HBUF + 65536;            // 32*256 bf16   = 16384
constexpr size_t WS_WXBT = WS_RBUF + 16384;            // 480*512 bf16  = 491520
constexpr size_t WS_EMB  = WS_WXBT + 491520;           // 8192*512 bf16 = 8388608
constexpr size_t WS_MIN  = WS_WXBT + 491520;           // 581888
constexpr size_t WS_FULL = WS_EMB + 8388608;           // 8970496
constexpr size_t WS_ZERO = WS_RBUF + 16384;            // bars + h0 + r0

__device__ __forceinline__ unsigned short f2b(float f) {
  unsigned u = __builtin_bit_cast(unsigned, f);
  u += 0x7fffu + ((u >> 16) & 1u);
  return (unsigned short)(u >> 16);
}
__device__ __forceinline__ float b2f(unsigned short us) {
  return __builtin_bit_cast(float, ((unsigned)us) << 16);
}
__device__ __forceinline__ float sigf(float x) { return 1.0f / (1.0f + expf(-x)); }
__device__ __forceinline__ float softplusf(float x) { return (x > 20.0f) ? x : log1pf(expf(x)); }
__device__ __forceinline__ float wsum(float v) {
  #pragma unroll
  for (int o = 32; o; o >>= 1) v += __shfl_xor(v, o, 64);
  return v;
}
__device__ __forceinline__ float wmaxr(float v) {
  #pragma unroll
  for (int o = 32; o; o >>= 1) v = fmaxf(v, __shfl_xor(v, o, 64));
  return v;
}
__device__ __forceinline__ f32x4 mfma16(bf16x8 a, bf16x8 b, f32x4 c) {
  return __builtin_amdgcn_mfma_f32_16x16x32_bf16(a, b, c, 0, 0, 0);
}

// MALL write-through / MALL-direct data movement (relaxed agent atomics)
__device__ __forceinline__ void st_u64(u64* p, u64 v) {
  __hip_atomic_store(p, v, __ATOMIC_RELAXED, __HIP_MEMORY_SCOPE_AGENT);
}
__device__ __forceinline__ u64 ld_u64(const u64* p) {
  return __hip_atomic_load(p, __ATOMIC_RELAXED, __HIP_MEMORY_SCOPE_AGENT);
}
struct alignas(16) U64x2 { u64 a, b; };
__device__ __forceinline__ bf16x8 ld_bf16x8_mall(const unsigned short* p) {
  U64x2 v;
  v.a = ld_u64((const u64*)p);
  v.b = ld_u64((const u64*)p + 1);
  return __builtin_bit_cast(bf16x8, v);
}

// Grid barrier: parallel arrival flags, master scan, single release flag.
// Monotonic seq, flags never reset. ALL RELAXED (no L2 maintenance ops);
// vmcnt(0) drain comes from the __syncthreads() codegen at entry.
__device__ __forceinline__ void gbar(unsigned* bars, unsigned seq) {
  __syncthreads();   // drains vmcnt -> prior MALL write-through stores visible
  const int tid = threadIdx.x;
  unsigned* rel = bars + NBLK * 16;
  if (blockIdx.x == (unsigned)MASTER) {
    if (tid == 0)
      __hip_atomic_store(&bars[MASTER * 16], seq, __ATOMIC_RELAXED, __HIP_MEMORY_SCOPE_AGENT);
    if (tid < 64) {
      unsigned a0 = 0, a1 = 0;
      const int i0 = tid * 2, i1 = tid * 2 + 1;
      for (;;) {
        if (a0 < seq) a0 = __hip_atomic_load(&bars[i0 * 16], __ATOMIC_RELAXED, __HIP_MEMORY_SCOPE_AGENT);
        if (a1 < seq) a1 = __hip_atomic_load(&bars[i1 * 16], __ATOMIC_RELAXED, __HIP_MEMORY_SCOPE_AGENT);
        if (__all(a0 >= seq && a1 >= seq)) break;
        __builtin_amdgcn_s_sleep(1);
      }
      if (tid == 0)
        __hip_atomic_store(rel, seq, __ATOMIC_RELAXED, __HIP_MEMORY_SCOPE_AGENT);
    }
  } else {
    if (tid == 0) {
      __hip_atomic_store(&bars[blockIdx.x * 16], seq, __ATOMIC_RELAXED, __HIP_MEMORY_SCOPE_AGENT);
      while (__hip_atomic_load(rel, __ATOMIC_RELAXED, __HIP_MEMORY_SCOPE_AGENT) < seq)
        __builtin_amdgcn_s_sleep(1);
    }
  }
  __builtin_amdgcn_fence(__ATOMIC_ACQUIRE, "workgroup");  // compile-order only
  __syncthreads();
}

__global__ __launch_bounds__(BS, 1) void dnc_kernel(
    const int* __restrict__ src, const float* __restrict__ emb,
    const float* __restrict__ Wih, const float* __restrict__ Whh,
    const float* __restrict__ b_lstm, const float* __restrict__ W_xi,
    const float* __restrict__ b_xi, const float* __restrict__ W_out,
    const float* __restrict__ b_out, float* __restrict__ out,
    unsigned* __restrict__ bars, unsigned short* __restrict__ hbuf,
    unsigned short* __restrict__ rbuf, unsigned short* __restrict__ wxbT_,
    unsigned short* __restrict__ embbuf_)
{
  extern __shared__ char smem[];
  __bf16* lWg  = (__bf16*)(smem + OFF_WG);
  __bf16* lWo  = (__bf16*)(smem + OFF_WO);
  float*  gt   = (float*)(smem + OFF_GT);
  float*  cst  = (float*)(smem + OFF_CST);
  float*  hl   = (float*)(smem + OFF_HL);
  __bf16* hlb  = (__bf16*)(smem + OFF_HLB);
  char*   dnc  = smem + OFF_DNC;
  float* Ml   = (float*)(dnc + D_M);
  float* Ll   = (float*)(dnc + D_L);
  float* xir  = (float*)(dnc + D_XIR);
  float* wrl  = (float*)(dnc + D_WR);
  float* fwd  = (float*)(dnc + D_FWD);
  float* bwd  = (float*)(dnc + D_BWD);
  float* simr = (float*)(dnc + D_SIMR);
  float* uu   = (float*)(dnc + D_VEC);
  float* pp   = uu + 64;
  float* wwl  = uu + 128;
  float* aas  = uu + 192;
  float* nrmo = uu + 256;
  float* nrmn = uu + 320;
  float* simw = uu + 384;
  float* er   = uu + 448;
  float* scal = (float*)(dnc + D_SCAL);
  // scal: [0]beta_w [1]g_a [2]g_w [3]wknrm [4..7]beta_r [8..11]rkn [12..15]free [16..27]pi

  const int tid  = threadIdx.x;
  const int blk  = blockIdx.x;
  const int lane = tid & 63;
  const int wv   = tid >> 6;
  const int q    = lane >> 4;
  const int n16  = lane & 15;
  const int j0   = blk << 2;    // h slice: columns j0..j0+3
  const __bf16* wxbT = (const __bf16*)wxbT_;
  const __bf16* embbuf = (const __bf16*)embbuf_;

  // ---------------- prepass ----------------
  for (int e = tid; e < 16 * KG; e += BS) {
    int k = e >> 4, cc = e & 15;
    int gcol = ((cc >> 2) << 9) + j0 + (cc & 3);   // gate*512 + h-col
    float w = (k < 768) ? Wih[k * 2048 + gcol] : Whh[(k - 768) * 2048 + gcol];
    lWg[cc * KGP + k] = (__bf16)w;
  }
  if (blk >= 64 && blk < 96) {
    for (int e = tid; e < 16 * 768; e += BS) {
      int k = e >> 4, cc = e & 15;
      int col = ((blk - 64) << 4) + cc;
      lWo[cc * WOP + k] = (__bf16)W_out[k * HH + col];
    }
  }
  if (wxbT_) {   // W_xi^T -> bf16 [col][k] workspace (write-through)
    for (int f = blk * BS + tid; f < XI * 128; f += NBLK * BS) {
      int col = f >> 7, k4 = (f & 127) << 2;
      u64 pk = 0;
      #pragma unroll
      for (int j = 0; j < 4; ++j) {
        unsigned short us = f2b(W_xi[(size_t)(k4 + j) * XI + col]);
        pk |= (u64)us << (16 * j);
      }
      st_u64((u64*)(wxbT_ + (size_t)col * 512 + k4), pk);
    }
  }
  if (embbuf_) { // gather emb[src] -> bf16 workspace (write-through)
    for (int rr = blk * 2 + (tid >> 7); rr < BQ * TT; rr += NBLK * 2) {
      const int t128 = tid & 127;
      const float* s = emb + (size_t)src[rr] * HH;
      float4 v = *(const float4*)(s + t128 * 4);
      u64 pk = (u64)f2b(v.x) | ((u64)f2b(v.y) << 16)
             | ((u64)f2b(v.z) << 32) | ((u64)f2b(v.w) << 48);
      st_u64((u64*)(embbuf_ + (size_t)rr * HH + t128 * 4), pk);
    }
  }
  if (tid < 128) cst[tid] = 0.0f;
  if (blk < BQ) {
    for (int e = tid; e < 64 * 65; e += BS) { Ml[e] = 0.0f; Ll[e] = 0.0f; }
    if (tid < 64) { uu[tid] = 0.0f; pp[tid] = 0.0f; wwl[tid] = 0.0f; }
    wrl[tid] = 0.0f;
  }
  gbar(bars, 1u);

  // y-phase: computes y_{t-1}; valid t in [1..TT]; runs on waves 2,3
  auto do_y = [&](int t) {
    const unsigned short* hp = hbuf + ((t + 1) & 1) * (BQ * HH);
    const int mt = wv - 2;
    const int bb = (mt << 4) + n16;
    f32x4 a0 = {0.f, 0.f, 0.f, 0.f}, a1 = {0.f, 0.f, 0.f, 0.f};
    #pragma unroll
    for (int ks = 0; ks < 24; ++ks) {
      const int kq = (ks << 5) + (q << 3);
      bf16x8 A = (ks < 16) ? ld_bf16x8_mall(hp + bb * HH + kq)
                           : ld_bf16x8_mall(rbuf + bb * (RH * NC) + (kq - 512));
      bf16x8 Bf = *(const bf16x8*)(lWo + n16 * WOP + kq);
      if (ks & 1) a1 = mfma16(A, Bf, a1); else a0 = mfma16(A, Bf, a0);
    }
    const int col = ((blk - 64) << 4) + n16;
    const float bias = b_out[col];
    #pragma unroll
    for (int j = 0; j < 4; ++j) {
      int row = (mt << 4) + (q << 2) + j;
      float y = a0[j] + a1[j] + bias;
      y = fminf(fmaxf(y, -CLIPV), CLIPV);
      out[(size_t)row * (TT * HH) + (size_t)(t - 1) * HH + col] = y;
    }
  };

  unsigned seq = 2u;
  for (int t = 0; t < TT; ++t) {
    const unsigned short* hprev = hbuf + ((t + 1) & 1) * (BQ * HH);
    unsigned short* hcur = hbuf + (t & 1) * (BQ * HH);

    // ---------------- phase A: gates (waves 0,1) + y_{t-1} (waves 2,3, blocks 64..95)
    if (wv < 2) {
      const int bb = (wv << 4) + n16;
      const __bf16* eb = embbuf ? (embbuf + ((size_t)bb * TT + t) * HH) : nullptr;
      const float* ep = embbuf ? nullptr
                               : (emb + (size_t)src[bb * TT + t] * HH + (q << 3));
      f32x4 a0 = {0.f, 0.f, 0.f, 0.f}, a1 = {0.f, 0.f, 0.f, 0.f};
      #pragma unroll
      for (int ks = 0; ks < 40; ++ks) {
        const int kq = (ks << 5) + (q << 3);
        bf16x8 A;
        if (ks < 16) {
          if (eb) {
            A = *(const bf16x8*)(eb + kq);   // plain: write-once, L2-warm
          } else {
            const float* p = ep + (ks << 5);
            #pragma unroll
            for (int j = 0; j < 8; ++j) A[j] = (__bf16)p[j];
          }
        } else if (ks < 24) {
          A = ld_bf16x8_mall(rbuf + bb * (RH * NC) + (kq - 512));
        } else {
          A = ld_bf16x8_mall(hprev + bb * HH + (kq - 768));
        }
        bf16x8 Bf = *(const bf16x8*)(lWg + n16 * KGP + kq);
        if (ks & 1) a1 = mfma16(A, Bf, a1); else a0 = mfma16(A, Bf, a0);
      }
      const int gcol = ((n16 >> 2) << 9) + j0 + (n16 & 3);
      const float bias = b_lstm[gcol];
      #pragma unroll
      for (int j = 0; j < 4; ++j)
        gt[((wv << 4) + (q << 2) + j) * 17 + n16] = a0[j] + a1[j] + bias;
    } else if (blk >= 64 && blk < 96 && t > 0) {
      do_y(t);
    }
    __syncthreads();
    if (tid < BQ) {            // LSTM update: batch=tid, our 4 h-columns
      const int b = tid;
      u64 hv = 0;
      #pragma unroll
      for (int i = 0; i < 4; ++i) {
        float g_i = gt[b * 17 + i],     g_f = gt[b * 17 + 4 + i];
        float g_g = gt[b * 17 + 8 + i], g_o = gt[b * 17 + 12 + i];
        float c = cst[b * 4 + i];
        c = sigf(g_f) * c + sigf(g_i) * tanhf(g_g);
        float h = sigf(g_o) * tanhf(c);
        cst[b * 4 + i] = c;
        hv |= (u64)f2b(h) << (16 * i);
      }
      st_u64((u64*)(hcur + b * HH + j0), hv);
    }
    gbar(bars, seq++);

    // ---------------- phase C: xi (MFMA) + DNC update, one block per batch
    if (blk < BQ) {
      if (tid < 128) {         // h_t[blk,:] -> LDS (f32 + bf16)
        u64 hv = ld_u64((const u64*)(hcur + blk * HH + tid * 4));
        #pragma unroll
        for (int i = 0; i < 4; ++i) {
          unsigned short us = (unsigned short)(hv >> (16 * i));
          hl[tid * 4 + i]  = b2f(us);
          hlb[tid * 4 + i] = __builtin_bit_cast(__bf16, us);
        }
      }
      __syncthreads();
      // xi = h @ W_xi + b_xi via MFMA: wave wv owns col-tiles ct0..ct0+7 (<30)
      {
        constexpr int TPW = 8;
        f32x4 acc[TPW];
        #pragma unroll
        for (int i = 0; i < TPW; ++i) acc[i] = f32x4{0.f, 0.f, 0.f, 0.f};
        const int ct0 = wv * TPW;
        const int ntile = (ct0 + TPW <= 30) ? TPW : (30 - ct0);
        for (int kt = 0; kt < 16; ++kt) {
          bf16x8 Bf;
          #pragma unroll
          for (int j = 0; j < 8; ++j)
            Bf[j] = (n16 == 0) ? hlb[kt * 32 + (q << 3) + j] : (__bf16)0.0f;
          if (wxbT) {
            #pragma unroll
            for (int i = 0; i < TPW; ++i) {
              if (i < ntile) {
                const __bf16* ap = wxbT + (size_t)((ct0 + i) * 16 + n16) * 512
                                        + kt * 32 + (q << 3);
                acc[i] = mfma16(*(const bf16x8*)ap, Bf, acc[i]);
              }
            }
          } else {
            #pragma unroll
            for (int i = 0; i < TPW; ++i) {
              if (i < ntile) {
                const int col = (ct0 + i) * 16 + n16;
                bf16x8 Af;
                #pragma unroll
                for (int j = 0; j < 8; ++j)
                  Af[j] = (col < XI) ? (__bf16)W_xi[(size_t)(kt * 32 + (q << 3) + j) * XI + col]
                                     : (__bf16)0.0f;
                acc[i] = mfma16(Af, Bf, acc[i]);
              }
            }
          }
        }
        if (n16 == 0) {
          const int rowb = (lane >> 4) * 4;
          #pragma unroll
          for (int i = 0; i < TPW; ++i) {
            if (i < ntile) {
              #pragma unroll
              for (int j = 0; j < 4; ++j) {
                int col = (ct0 + i) * 16 + rowb + j;
                if (col < XI) xir[col] = acc[i][j] + b_xi[col];
              }
            }
          }
        }
      }
      __syncthreads();
      if (tid == 0) {
        scal[0] = 1.0f + softplusf(xir[324]);   // beta_w
        scal[1] = sigf(xir[457]);               // g_a
        scal[2] = sigf(xir[458]);               // g_w
      }
      if (tid >= 4 && tid < 8) {
        int r = tid - 4;
        scal[4 + r]  = 1.0f + softplusf(xir[256 + r]);  // beta_r
        scal[12 + r] = sigf(xir[453 + r]);              // free
        float p0 = xir[459 + r * 3], p1 = xir[460 + r * 3], p2 = xir[461 + r * 3];
        float m = fmaxf(p0, fmaxf(p1, p2));
        float e0 = expf(p0 - m), e1 = expf(p1 - m), e2 = expf(p2 - m);
        float s = e0 + e1 + e2;
        scal[16 + r * 3 + 0] = e0 / s;
        scal[16 + r * 3 + 1] = e1 / s;
        scal[16 + r * 3 + 2] = e2 / s;
      }
      if (tid >= 64 && tid < 128) er[tid - 64] = sigf(xir[325 + (tid - 64)]);
      __syncthreads();
      // -- old norms / write-key sim / usage + stable sort + allocation
      if (wv == 0) {
        float s = 0.f;
        for (int w = 0; w < 64; ++w) { float m = Ml[lane * 65 + w]; s += m * m; }
        nrmo[lane] = sqrtf(s) + EPSV;
      } else if (wv == 1) {
        float d = 0.f;
        for (int w = 0; w < 64; ++w) d += Ml[lane * 65 + w] * xir[260 + w];
        simw[lane] = d;
        float v = xir[260 + lane];
        float s2 = wsum(v * v);
        if (lane == 0) scal[3] = sqrtf(s2) + EPSV;
      } else if (wv == 2) {
        float psi = 1.f;
        #pragma unroll
        for (int r = 0; r < 4; ++r) psi *= (1.f - scal[12 + r] * wrl[r * 64 + lane]);
        float un = uu[lane], w_ = wwl[lane];
        un = (un + w_ - un * w_) * psi;
        uu[lane] = un;
        // stable bitonic argsort ascending by (u, index)
        float v = un; int id = lane;
        for (int k = 2; k <= 64; k <<= 1) {
          for (int j2 = k >> 1; j2 > 0; j2 >>= 1) {
            float ov = __shfl_xor(v, j2, 64);
            int   oi = __shfl_xor(id, j2, 64);
            bool up    = ((lane & k) == 0);
            bool lower = ((lane & j2) == 0);
            bool lt = (v < ov) || (v == ov && id < oi);
            bool keep = (lower == up) ? lt : !lt;
            if (!keep) { v = ov; id = oi; }
          }
        }
        float cp = v;
        for (int d2 = 1; d2 < 64; d2 <<= 1) {
          float o = __shfl_up(cp, d2, 64);
          if (lane >= d2) cp *= o;
        }
        float pe = __shfl_up(cp, 1, 64);
        if (lane == 0) pe = 1.0f;
        aas[id] = (1.0f - v) * pe;
      }
      __syncthreads();
      // -- write content weights -> ww
      if (wv == 0) {
        float x = simw[lane] / (nrmo[lane] * scal[3]) * scal[0];
        float mx = wmaxr(x);
        float e = expf(x - mx);
        float s = wsum(e);
        float cw = e / s;
        wwl[lane] = scal[2] * (scal[1] * aas[lane] + (1.f - scal[1]) * cw);
      }
      __syncthreads();
      // -- M and L updates (old p)
      {
        const int n = tid >> 2, c4 = (tid & 3) << 4;
        float wwn = wwl[n];
        #pragma unroll
        for (int w = 0; w < 16; ++w) {
          int wj = c4 + w;
          Ml[n * 65 + wj] = Ml[n * 65 + wj] * (1.f - wwn * er[wj]) + wwn * xir[389 + wj];
        }
        #pragma unroll
        for (int w = 0; w < 16; ++w) {
          int m2 = c4 + w;
          float Lv = (n == m2) ? 0.f
                   : ((1.f - wwn - wwl[m2]) * Ll[n * 65 + m2] + wwn * pp[m2]);
          Ll[n * 65 + m2] = Lv;
        }
      }
      __syncthreads();
      // -- fwd/bwd (old wr, new L), read-key sims (new M), new norms
      {
        float f = 0.f, bw2 = 0.f, d = 0.f;
        for (int m2 = 0; m2 < 64; ++m2) {
          float wrm = wrl[wv * 64 + m2];
          f   += Ll[lane * 65 + m2] * wrm;
          bw2 += Ll[m2 * 65 + lane] * wrm;
        }
        fwd[wv * 64 + lane] = f;
        bwd[wv * 64 + lane] = bw2;
        for (int w = 0; w < 64; ++w) d += Ml[lane * 65 + w] * xir[wv * 64 + w];
        simr[wv * 64 + lane] = d;
        float v = xir[wv * 64 + lane];
        float s2 = wsum(v * v);
        if (lane == 0) scal[8 + wv] = sqrtf(s2) + EPSV;
        if (wv == 0) {
          float s = 0.f;
          for (int w = 0; w < 64; ++w) { float m = Ml[lane * 65 + w]; s += m * m; }
          nrmn[lane] = sqrtf(s) + EPSV;
        }
      }
      __syncthreads();
      // -- read content weights, new wr, p update
      {
        float x = simr[wv * 64 + lane] / (nrmn[lane] * scal[8 + wv]) * scal[4 + wv];
        float mx = wmaxr(x);
        float e = expf(x - mx);
        float s = wsum(e);
        float cw = e / s;
        float wrn = scal[16 + wv * 3 + 0] * bwd[wv * 64 + lane]
                  + scal[16 + wv * 3 + 1] * cw
                  + scal[16 + wv * 3 + 2] * fwd[wv * 64 + lane];
        wrl[wv * 64 + lane] = wrn;
        if (wv == 3) {
          float s3 = wsum(wwl[lane]);
          pp[lane] = (1.f - s3) * pp[lane] + wwl[lane];
        }
      }
      __syncthreads();
      // -- r = wr @ M -> rbuf (bf16, packed u64 write-through)
      {
        float rv = 0.f;
        for (int n2 = 0; n2 < 64; ++n2) rv += wrl[wv * 64 + n2] * Ml[n2 * 65 + lane];
        unsigned v0 = f2b(rv);
        unsigned v1 = __shfl_down(v0, 1, 64);
        unsigned v2 = __shfl_down(v0, 2, 64);
        unsigned v3 = __shfl_down(v0, 3, 64);
        if ((lane & 3) == 0) {
          u64 pk = (u64)v0 | ((u64)v1 << 16) | ((u64)v2 << 32) | ((u64)v3 << 48);
          st_u64((u64*)(rbuf + blk * (RH * NC) + wv * 64 + lane), pk);
        }
      }
    }
    gbar(bars, seq++);
  }

  // final y_{T-1}
  if (blk >= 64 && blk < 96 && wv >= 2) do_y(TT);
}

extern "C" void kernel_launch(void* const* d_in, const int* in_sizes, int n_in,
                              void* d_out, int out_size, void* d_ws, size_t ws_size,
                              hipStream_t stream) {
  const int*   src    = (const int*)d_in[0];
  const float* emb    = (const float*)d_in[2];
  const float* Wih    = (const float*)d_in[3];
  const float* Whh    = (const float*)d_in[4];
  const float* b_lstm = (const float*)d_in[5];
  const float* W_xi   = (const float*)d_in[6];
  const float* b_xi   = (const float*)d_in[7];
  const float* W_out  = (const float*)d_in[8];
  const float* b_out  = (const float*)d_in[9];
  float* out = (float*)d_out;

  char* ws = (char*)d_ws;
  unsigned*       bars   = (unsigned*)(ws + WS_BARS);
  unsigned short* hbuf   = (unsigned short*)(ws + WS_HBUF);
  unsigned short* rbuf   = (unsigned short*)(ws + WS_RBUF);
  unsigned short* wxbT   = (ws_size >= WS_MIN)  ? (unsigned short*)(ws + WS_WXBT) : nullptr;
  unsigned short* embbuf = (ws_size >= WS_FULL) ? (unsigned short*)(ws + WS_EMB)  : nullptr;

  hipMemsetAsync(d_ws, 0, WS_ZERO, stream);   // barrier flags + h0 + r0
  hipFuncSetAttribute((const void*)dnc_kernel,
                      hipFuncAttributeMaxDynamicSharedMemorySize, SMEM_BYTES);
  dnc_kernel<<<dim3(NBLK), dim3(BS), SMEM_BYTES, stream>>>(
      src, emb, Wih, Whh, b_lstm, W_xi, b_xi, W_out, b_out, out,
      bars, hbuf, rbuf, wxbT, embbuf);
}

// Round 5
// 11290.530 us; speedup vs baseline: 2.0390x; 1.0918x over previous
//
#include <hip/hip_runtime.h>

// Persistent-grid DNC encoder for MI355X (gfx950).
// 128 blocks x 256 threads, ~113KB LDS/block -> 1 block/CU -> co-resident.
// R5: split-phase producer/consumer pipeline. No aggregated grid barrier:
// producers publish per-block monotonic flags (hflag[128], rflag[32]) via
// relaxed agent atomics (MALL write-through); consumers poll exactly the
// flags they need right before the dependent compute. Gates x-part(t+1) is
// computed during DNC phase C(t) to hide its latency; h-part waits h-flags,
// r-part waits r-flags. 2 one-hop syncs per step instead of 2 five-hop
// barriers.

constexpr int NBLK = 128;
constexpr int BS   = 256;
constexpr int BQ   = 32;
constexpr int TT   = 256;
constexpr int HH   = 512;
constexpr int RH   = 4;
constexpr int NC   = 64;
constexpr int XI   = 471;
constexpr int KG   = 1280;    // gates K = 512(x)+256(r)+512(h)
constexpr int KGP  = 1288;    // padded LDS K stride (bf16)
constexpr int WOP  = 776;     // padded W_out K stride
constexpr float CLIPV = 50000.0f;
constexpr float EPSV  = 1e-6f;

typedef __bf16 bf16x8 __attribute__((ext_vector_type(8)));
typedef float  f32x4  __attribute__((ext_vector_type(4)));
typedef unsigned long long u64;

// ---- LDS layout (bytes) ----
constexpr int OFF_WG   = 0;                      // 16*KGP bf16 = 41216
constexpr int OFF_WO   = OFF_WG  + 16*KGP*2;     // 16*WOP bf16 = 24832
constexpr int OFF_GT   = OFF_WO  + 16*WOP*2;     // 32*17 f32   = 2176
constexpr int OFF_CST  = OFF_GT  + 32*17*4;      // 128 f32     = 512
constexpr int OFF_HL   = OFF_CST + 512;          // 512 f32     = 2048
constexpr int OFF_HLB  = OFF_HL  + 2048;         // 512 bf16    = 1024
constexpr int OFF_DNC  = OFF_HLB + 1024;
constexpr int D_M    = 0;                        // 64*65 f32
constexpr int D_L    = D_M   + 64*65*4;
constexpr int D_XIR  = D_L   + 64*65*4;          // 480 f32
constexpr int D_WR   = D_XIR + 480*4;
constexpr int D_FWD  = D_WR  + 256*4;
constexpr int D_BWD  = D_FWD + 256*4;
constexpr int D_SIMR = D_BWD + 256*4;
constexpr int D_VEC  = D_SIMR+ 256*4;            // 8 arrays of 64 f32
constexpr int D_SCAL = D_VEC + 8*64*4;           // 32 f32
constexpr int SMEM_BYTES = OFF_DNC + D_SCAL + 32*4;   // 113280

// ---- workspace layout (bytes) ----
constexpr size_t WS_HFLG = 0;                          // 128 slots * 64B
constexpr size_t WS_RFLG = 8192;                       // 32 slots * 64B
constexpr size_t WS_HBUF = 8192 + 2048;                // 2*32*512 bf16 = 65536
constexpr size_t WS_RBUF = WS_HBUF + 65536;            // 32*256 bf16   = 16384
constexpr size_t WS_WXBT = WS_RBUF + 16384;            // 480*512 bf16  = 491520
constexpr size_t WS_EMB  = WS_WXBT + 491520;           // 8192*512 bf16 = 8388608
constexpr size_t WS_MIN  = WS_WXBT + 491520;
constexpr size_t WS_FULL = WS_EMB + 8388608;
constexpr size_t WS_ZERO = WS_RBUF + 16384;            // flags + hbuf + rbuf

__device__ __forceinline__ unsigned short f2b(float f) {
  unsigned u = __builtin_bit_cast(unsigned, f);
  u += 0x7fffu + ((u >> 16) & 1u);
  return (unsigned short)(u >> 16);
}
__device__ __forceinline__ float b2f(unsigned short us) {
  return __builtin_bit_cast(float, ((unsigned)us) << 16);
}
__device__ __forceinline__ float sigf(float x) { return 1.0f / (1.0f + expf(-x)); }
__device__ __forceinline__ float softplusf(float x) { return (x > 20.0f) ? x : log1pf(expf(x)); }
__device__ __forceinline__ float wsum(float v) {
  #pragma unroll
  for (int o = 32; o; o >>= 1) v += __shfl_xor(v, o, 64);
  return v;
}
__device__ __forceinline__ float wmaxr(float v) {
  #pragma unroll
  for (int o = 32; o; o >>= 1) v = fmaxf(v, __shfl_xor(v, o, 64));
  return v;
}
__device__ __forceinline__ f32x4 mfma16(bf16x8 a, bf16x8 b, f32x4 c) {
  return __builtin_amdgcn_mfma_f32_16x16x32_bf16(a, b, c, 0, 0, 0);
}

// MALL write-through / MALL-direct (relaxed agent atomics)
__device__ __forceinline__ void st_u64(u64* p, u64 v) {
  __hip_atomic_store(p, v, __ATOMIC_RELAXED, __HIP_MEMORY_SCOPE_AGENT);
}
__device__ __forceinline__ u64 ld_u64(const u64* p) {
  return __hip_atomic_load(p, __ATOMIC_RELAXED, __HIP_MEMORY_SCOPE_AGENT);
}
__device__ __forceinline__ void st_flag(unsigned* p, unsigned v) {
  __hip_atomic_store(p, v, __ATOMIC_RELAXED, __HIP_MEMORY_SCOPE_AGENT);
}
__device__ __forceinline__ unsigned ld_flag(const unsigned* p) {
  return __hip_atomic_load(p, __ATOMIC_RELAXED, __HIP_MEMORY_SCOPE_AGENT);
}
struct alignas(16) U64x2 { u64 a, b; };
__device__ __forceinline__ bf16x8 ld_bf16x8_mall(const unsigned short* p) {
  U64x2 v;
  v.a = ld_u64((const u64*)p);
  v.b = ld_u64((const u64*)p + 1);
  return __builtin_bit_cast(bf16x8, v);
}

// wait until all 128 h-flags >= seq (wave 0 polls, block-wide release)
__device__ __forceinline__ void wait_h(const unsigned* hflag, unsigned seq) {
  if ((threadIdx.x >> 6) == 0) {
    const int lane = threadIdx.x & 63;
    unsigned a0 = 0, a1 = 0;
    for (;;) {
      if (a0 < seq) a0 = ld_flag(hflag + lane * 16);
      if (a1 < seq) a1 = ld_flag(hflag + (64 + lane) * 16);
      if (__all(a0 >= seq && a1 >= seq)) break;
      __builtin_amdgcn_s_sleep(1);
    }
  }
  __builtin_amdgcn_fence(__ATOMIC_ACQUIRE, "workgroup");
  __syncthreads();
}
// wait until all 32 r-flags >= seq
__device__ __forceinline__ void wait_r(const unsigned* rflag, unsigned seq) {
  if ((threadIdx.x >> 6) == 0) {
    const int lane = threadIdx.x & 63;
    unsigned a = (lane < 32) ? 0u : 0xffffffffu;
    for (;;) {
      if (a < seq) a = ld_flag(rflag + lane * 16);
      if (__all(a >= seq)) break;
      __builtin_amdgcn_s_sleep(1);
    }
  }
  __builtin_amdgcn_fence(__ATOMIC_ACQUIRE, "workgroup");
  __syncthreads();
}

__global__ __launch_bounds__(BS, 1) void dnc_kernel(
    const int* __restrict__ src, const float* __restrict__ emb,
    const float* __restrict__ Wih, const float* __restrict__ Whh,
    const float* __restrict__ b_lstm, const float* __restrict__ W_xi,
    const float* __restrict__ b_xi, const float* __restrict__ W_out,
    const float* __restrict__ b_out, float* __restrict__ out,
    unsigned* __restrict__ hflag, unsigned* __restrict__ rflag,
    unsigned short* __restrict__ hbuf, unsigned short* __restrict__ rbuf,
    unsigned short* __restrict__ wxbT_, unsigned short* __restrict__ embbuf_)
{
  extern __shared__ char smem[];
  __bf16* lWg  = (__bf16*)(smem + OFF_WG);
  __bf16* lWo  = (__bf16*)(smem + OFF_WO);
  float*  gt   = (float*)(smem + OFF_GT);
  float*  cst  = (float*)(smem + OFF_CST);
  float*  hl   = (float*)(smem + OFF_HL);
  __bf16* hlb  = (__bf16*)(smem + OFF_HLB);
  char*   dnc  = smem + OFF_DNC;
  float* Ml   = (float*)(dnc + D_M);
  float* Ll   = (float*)(dnc + D_L);
  float* xir  = (float*)(dnc + D_XIR);
  float* wrl  = (float*)(dnc + D_WR);
  float* fwd  = (float*)(dnc + D_FWD);
  float* bwd  = (float*)(dnc + D_BWD);
  float* simr = (float*)(dnc + D_SIMR);
  float* uu   = (float*)(dnc + D_VEC);
  float* pp   = uu + 64;
  float* wwl  = uu + 128;
  float* aas  = uu + 192;
  float* nrmo = uu + 256;
  float* nrmn = uu + 320;
  float* simw = uu + 384;
  float* er   = uu + 448;
  float* scal = (float*)(dnc + D_SCAL);
  // scal: [0]beta_w [1]g_a [2]g_w [3]wknrm [4..7]beta_r [8..11]rkn [12..15]free [16..27]pi

  const int tid  = threadIdx.x;
  const int blk  = blockIdx.x;
  const int lane = tid & 63;
  const int wv   = tid >> 6;
  const int q    = lane >> 4;
  const int n16  = lane & 15;
  const int j0   = blk << 2;    // h slice: columns j0..j0+3
  const __bf16* wxbT = (const __bf16*)wxbT_;
  const __bf16* embbuf = (const __bf16*)embbuf_;
  const bool is_dnc = (blk < BQ);
  const bool is_y   = (blk >= 64 && blk < 96);

  // ---------------- prepass ----------------
  for (int e = tid; e < 16 * KG; e += BS) {
    int k = e >> 4, cc = e & 15;
    int gcol = ((cc >> 2) << 9) + j0 + (cc & 3);   // gate*512 + h-col
    float w = (k < 768) ? Wih[k * 2048 + gcol] : Whh[(k - 768) * 2048 + gcol];
    lWg[cc * KGP + k] = (__bf16)w;
  }
  if (is_y) {
    for (int e = tid; e < 16 * 768; e += BS) {
      int k = e >> 4, cc = e & 15;
      int col = ((blk - 64) << 4) + cc;
      lWo[cc * WOP + k] = (__bf16)W_out[k * HH + col];
    }
  }
  if (wxbT_) {   // W_xi^T -> bf16 [col][k] (MALL write-through)
    for (int f = blk * BS + tid; f < XI * 128; f += NBLK * BS) {
      int col = f >> 7, k4 = (f & 127) << 2;
      u64 pk = 0;
      #pragma unroll
      for (int j = 0; j < 4; ++j) {
        unsigned short us = f2b(W_xi[(size_t)(k4 + j) * XI + col]);
        pk |= (u64)us << (16 * j);
      }
      st_u64((u64*)(wxbT_ + (size_t)col * 512 + k4), pk);
    }
  }
  if (embbuf_) { // gather emb[src] -> bf16 (MALL write-through)
    for (int rr = blk * 2 + (tid >> 7); rr < BQ * TT; rr += NBLK * 2) {
      const int t128 = tid & 127;
      const float* s = emb + (size_t)src[rr] * HH;
      float4 v = *(const float4*)(s + t128 * 4);
      u64 pk = (u64)f2b(v.x) | ((u64)f2b(v.y) << 16)
             | ((u64)f2b(v.z) << 32) | ((u64)f2b(v.w) << 48);
      st_u64((u64*)(embbuf_ + (size_t)rr * HH + t128 * 4), pk);
    }
  }
  if (tid < 128) cst[tid] = 0.0f;
  if (is_dnc) {
    for (int e = tid; e < 64 * 65; e += BS) { Ml[e] = 0.0f; Ll[e] = 0.0f; }
    if (tid < 64) { uu[tid] = 0.0f; pp[tid] = 0.0f; wwl[tid] = 0.0f; }
    wrl[tid] = 0.0f;
  }
  __syncthreads();
  if (tid == 0) st_flag(hflag + blk * 16, 1u);   // prepass published

  // persistent gates accumulators (waves 0,1)
  f32x4 ax0 = {0.f, 0.f, 0.f, 0.f}, ax1 = {0.f, 0.f, 0.f, 0.f};
  const int bb = ((wv & 1) << 4) + n16;          // gates A-row (waves 0,1)

  // x-part: 16 MFMAs (embedding of step tt)
  auto x_mfmas = [&](int tt) {
    const __bf16* eb = embbuf ? (embbuf + ((size_t)bb * TT + tt) * HH) : nullptr;
    const float* ep = embbuf ? nullptr
                             : (emb + (size_t)src[bb * TT + tt] * HH + (q << 3));
    #pragma unroll
    for (int ks = 0; ks < 16; ++ks) {
      const int kq = (ks << 5) + (q << 3);
      bf16x8 A;
      if (eb) {
        A = *(const bf16x8*)(eb + kq);
      } else {
        const float* p = ep + (ks << 5);
        #pragma unroll
        for (int j = 0; j < 8; ++j) A[j] = (__bf16)p[j];
      }
      bf16x8 Bf = *(const bf16x8*)(lWg + n16 * KGP + kq);
      if (ks & 1) ax1 = mfma16(A, Bf, ax1); else ax0 = mfma16(A, Bf, ax0);
    }
  };
  // h-part: 16 MFMAs reading h(slot) MALL-direct
  auto h_mfmas = [&](int slot) {
    const unsigned short* hp = hbuf + slot * (BQ * HH);
    #pragma unroll
    for (int ks = 16; ks < 32; ++ks) {
      const int off = ((ks - 16) << 5) + (q << 3);
      bf16x8 A = ld_bf16x8_mall(hp + bb * HH + off);
      bf16x8 Bf = *(const bf16x8*)(lWg + n16 * KGP + 768 + off);
      if (ks & 1) ax1 = mfma16(A, Bf, ax1); else ax0 = mfma16(A, Bf, ax0);
    }
  };
  // r-part: 8 MFMAs reading rbuf MALL-direct; then write gt
  auto r_mfmas = [&]() {
    #pragma unroll
    for (int ks = 32; ks < 40; ++ks) {
      const int off = ((ks - 32) << 5) + (q << 3);
      bf16x8 A = ld_bf16x8_mall(rbuf + bb * (RH * NC) + off);
      bf16x8 Bf = *(const bf16x8*)(lWg + n16 * KGP + 512 + off);
      if (ks & 1) ax1 = mfma16(A, Bf, ax1); else ax0 = mfma16(A, Bf, ax0);
    }
    const int gcol = ((n16 >> 2) << 9) + j0 + (n16 & 3);
    const float bias = b_lstm[gcol];
    #pragma unroll
    for (int j = 0; j < 4; ++j)
      gt[(((wv & 1) << 4) + (q << 2) + j) * 17 + n16] = ax0[j] + ax1[j] + bias;
  };
  // y(t-1): waves 2,3 of y-blocks; needs h(t-1) and r(t-1)
  auto do_y = [&](int t) {
    const unsigned short* hp = hbuf + ((t + 1) & 1) * (BQ * HH);
    const int mt = wv - 2;
    const int bby = (mt << 4) + n16;
    f32x4 a0 = {0.f, 0.f, 0.f, 0.f}, a1 = {0.f, 0.f, 0.f, 0.f};
    #pragma unroll
    for (int ks = 0; ks < 24; ++ks) {
      const int kq = (ks << 5) + (q << 3);
      bf16x8 A = (ks < 16) ? ld_bf16x8_mall(hp + bby * HH + kq)
                           : ld_bf16x8_mall(rbuf + bby * (RH * NC) + (kq - 512));
      bf16x8 Bf = *(const bf16x8*)(lWo + n16 * WOP + kq);
      if (ks & 1) a1 = mfma16(A, Bf, a1); else a0 = mfma16(A, Bf, a0);
    }
    const int col = ((blk - 64) << 4) + n16;
    const float bias = b_out[col];
    #pragma unroll
    for (int j = 0; j < 4; ++j) {
      int row = (mt << 4) + (q << 2) + j;
      float y = a0[j] + a1[j] + bias;
      y = fminf(fmaxf(y, -CLIPV), CLIPV);
      out[(size_t)row * (TT * HH) + (size_t)(t - 1) * HH + col] = y;
    }
  };

  // pre-loop: wait for prepass publication, then x-part(0). h(-1)=0, r(-1)=0.
  wait_h(hflag, 1u);
  if (wv < 2) x_mfmas(0);

  for (int t = 0; t < TT; ++t) {
    unsigned short* hcur = hbuf + (t & 1) * (BQ * HH);

    wait_r(rflag, (unsigned)t);          // r(t-1) published (t=0: zeros)
    if (wv < 2) {
      r_mfmas();                          // gates(t) complete -> gt
    } else if (is_y && t > 0) {
      do_y(t);                            // y(t-1): h(t-1), r(t-1)
    }
    __syncthreads();
    if (tid < BQ) {                       // LSTM: batch=tid, 4 h-cols
      const int b = tid;
      u64 hv = 0;
      #pragma unroll
      for (int i = 0; i < 4; ++i) {
        float g_i = gt[b * 17 + i],     g_f = gt[b * 17 + 4 + i];
        float g_g = gt[b * 17 + 8 + i], g_o = gt[b * 17 + 12 + i];
        float c = cst[b * 4 + i];
        c = sigf(g_f) * c + sigf(g_i) * tanhf(g_g);
        float h = sigf(g_o) * tanhf(c);
        cst[b * 4 + i] = c;
        hv |= (u64)f2b(h) << (16 * i);
      }
      st_u64((u64*)(hcur + b * HH + j0), hv);
    }
    __syncthreads();                      // drain h stores to MALL
    if (tid == 0) st_flag(hflag + blk * 16, (unsigned)(t + 2));

    if (is_dnc) {
      wait_h(hflag, (unsigned)(t + 2));   // full h(t)
      // ---------------- phase C(t) ----------------
      if (tid < 128) {                    // h(t)[blk,:] -> LDS
        u64 hv = ld_u64((const u64*)(hcur + blk * HH + tid * 4));
        #pragma unroll
        for (int i = 0; i < 4; ++i) {
          unsigned short us = (unsigned short)(hv >> (16 * i));
          hl[tid * 4 + i]  = b2f(us);
          hlb[tid * 4 + i] = __builtin_bit_cast(__bf16, us);
        }
      }
      __syncthreads();
      // xi = h @ W_xi + b_xi via MFMA
      {
        constexpr int TPW = 8;
        f32x4 acc[TPW];
        #pragma unroll
        for (int i = 0; i < TPW; ++i) acc[i] = f32x4{0.f, 0.f, 0.f, 0.f};
        const int ct0 = wv * TPW;
        const int ntile = (ct0 + TPW <= 30) ? TPW : (30 - ct0);
        for (int kt = 0; kt < 16; ++kt) {
          bf16x8 Bf = {};
          if (n16 == 0) Bf = *(const bf16x8*)(hlb + kt * 32 + (q << 3));
          if (wxbT) {
            #pragma unroll
            for (int i = 0; i < TPW; ++i) {
              if (i < ntile) {
                const __bf16* ap = wxbT + (size_t)((ct0 + i) * 16 + n16) * 512
                                        + kt * 32 + (q << 3);
                acc[i] = mfma16(*(const bf16x8*)ap, Bf, acc[i]);
              }
            }
          } else {
            #pragma unroll
            for (int i = 0; i < TPW; ++i) {
              if (i < ntile) {
                const int col = (ct0 + i) * 16 + n16;
                bf16x8 Af;
                #pragma unroll
                for (int j = 0; j < 8; ++j)
                  Af[j] = (col < XI) ? (__bf16)W_xi[(size_t)(kt * 32 + (q << 3) + j) * XI + col]
                                     : (__bf16)0.0f;
                acc[i] = mfma16(Af, Bf, acc[i]);
              }
            }
          }
        }
        if (n16 == 0) {
          const int rowb = (lane >> 4) * 4;
          #pragma unroll
          for (int i = 0; i < TPW; ++i) {
            if (i < ntile) {
              #pragma unroll
              for (int j = 0; j < 4; ++j) {
                int col = (ct0 + i) * 16 + rowb + j;
                if (col < XI) xir[col] = acc[i][j] + b_xi[col];
              }
            }
          }
        }
      }
      __syncthreads();
      if (tid == 0) {
        scal[0] = 1.0f + softplusf(xir[324]);   // beta_w
        scal[1] = sigf(xir[457]);               // g_a
        scal[2] = sigf(xir[458]);               // g_w
      }
      if (tid >= 4 && tid < 8) {
        int r = tid - 4;
        scal[4 + r]  = 1.0f + softplusf(xir[256 + r]);  // beta_r
        scal[12 + r] = sigf(xir[453 + r]);              // free
        float p0 = xir[459 + r * 3], p1 = xir[460 + r * 3], p2 = xir[461 + r * 3];
        float m = fmaxf(p0, fmaxf(p1, p2));
        float e0 = expf(p0 - m), e1 = expf(p1 - m), e2 = expf(p2 - m);
        float s = e0 + e1 + e2;
        scal[16 + r * 3 + 0] = e0 / s;
        scal[16 + r * 3 + 1] = e1 / s;
        scal[16 + r * 3 + 2] = e2 / s;
      }
      if (tid >= 64 && tid < 128) er[tid - 64] = sigf(xir[325 + (tid - 64)]);
      __syncthreads();
      // -- old norms / write-key sim / usage + stable sort + allocation
      if (wv == 0) {
        float s = 0.f;
        for (int w = 0; w < 64; ++w) { float m = Ml[lane * 65 + w]; s += m * m; }
        nrmo[lane] = sqrtf(s) + EPSV;
      } else if (wv == 1) {
        float d = 0.f;
        for (int w = 0; w < 64; ++w) d += Ml[lane * 65 + w] * xir[260 + w];
        simw[lane] = d;
        float v = xir[260 + lane];
        float s2 = wsum(v * v);
        if (lane == 0) scal[3] = sqrtf(s2) + EPSV;
      } else if (wv == 2) {
        float psi = 1.f;
        #pragma unroll
        for (int r = 0; r < 4; ++r) psi *= (1.f - scal[12 + r] * wrl[r * 64 + lane]);
        float un = uu[lane], w_ = wwl[lane];
        un = (un + w_ - un * w_) * psi;
        uu[lane] = un;
        // stable bitonic argsort ascending by (u, index)
        float v = un; int id = lane;
        for (int k = 2; k <= 64; k <<= 1) {
          for (int j2 = k >> 1; j2 > 0; j2 >>= 1) {
            float ov = __shfl_xor(v, j2, 64);
            int   oi = __shfl_xor(id, j2, 64);
            bool up    = ((lane & k) == 0);
            bool lower = ((lane & j2) == 0);
            bool lt = (v < ov) || (v == ov && id < oi);
            bool keep = (lower == up) ? lt : !lt;
            if (!keep) { v = ov; id = oi; }
          }
        }
        float cp = v;
        for (int d2 = 1; d2 < 64; d2 <<= 1) {
          float o = __shfl_up(cp, d2, 64);
          if (lane >= d2) cp *= o;
        }
        float pe = __shfl_up(cp, 1, 64);
        if (lane == 0) pe = 1.0f;
        aas[id] = (1.0f - v) * pe;
      }
      __syncthreads();
      // -- write content weights -> ww
      if (wv == 0) {
        float x = simw[lane] / (nrmo[lane] * scal[3]) * scal[0];
        float mx = wmaxr(x);
        float e = expf(x - mx);
        float s = wsum(e);
        float cw = e / s;
        wwl[lane] = scal[2] * (scal[1] * aas[lane] + (1.f - scal[1]) * cw);
      }
      __syncthreads();
      // -- M and L updates (old p)
      {
        const int n = tid >> 2, c4 = (tid & 3) << 4;
        float wwn = wwl[n];
        #pragma unroll
        for (int w = 0; w < 16; ++w) {
          int wj = c4 + w;
          Ml[n * 65 + wj] = Ml[n * 65 + wj] * (1.f - wwn * er[wj]) + wwn * xir[389 + wj];
        }
        #pragma unroll
        for (int w = 0; w < 16; ++w) {
          int m2 = c4 + w;
          float Lv = (n == m2) ? 0.f
                   : ((1.f - wwn - wwl[m2]) * Ll[n * 65 + m2] + wwn * pp[m2]);
          Ll[n * 65 + m2] = Lv;
        }
      }
      __syncthreads();
      // -- fwd/bwd (old wr, new L), read-key sims (new M), new norms
      {
        float f = 0.f, bw2 = 0.f, d = 0.f;
        for (int m2 = 0; m2 < 64; ++m2) {
          float wrm = wrl[wv * 64 + m2];
          f   += Ll[lane * 65 + m2] * wrm;
          bw2 += Ll[m2 * 65 + lane] * wrm;
        }
        fwd[wv * 64 + lane] = f;
        bwd[wv * 64 + lane] = bw2;
        for (int w = 0; w < 64; ++w) d += Ml[lane * 65 + w] * xir[wv * 64 + w];
        simr[wv * 64 + lane] = d;
        float v = xir[wv * 64 + lane];
        float s2 = wsum(v * v);
        if (lane == 0) scal[8 + wv] = sqrtf(s2) + EPSV;
        if (wv == 0) {
          float s = 0.f;
          for (int w = 0; w < 64; ++w) { float m = Ml[lane * 65 + w]; s += m * m; }
          nrmn[lane] = sqrtf(s) + EPSV;
        }
      }
      __syncthreads();
      // -- read content weights, new wr, p update
      {
        float x = simr[wv * 64 + lane] / (nrmn[lane] * scal[8 + wv]) * scal[4 + wv];
        float mx = wmaxr(x);
        float e = expf(x - mx);
        float s = wsum(e);
        float cw = e / s;
        float wrn = scal[16 + wv * 3 + 0] * bwd[wv * 64 + lane]
                  + scal[16 + wv * 3 + 1] * cw
                  + scal[16 + wv * 3 + 2] * fwd[wv * 64 + lane];
        wrl[wv * 64 + lane] = wrn;
        if (wv == 3) {
          float s3 = wsum(wwl[lane]);
          pp[lane] = (1.f - s3) * pp[lane] + wwl[lane];
        }
      }
      __syncthreads();
      // -- r(t) = wr @ M -> rbuf (bf16 packed, MALL write-through)
      {
        float rv = 0.f;
        for (int n2 = 0; n2 < 64; ++n2) rv += wrl[wv * 64 + n2] * Ml[n2 * 65 + lane];
        unsigned v0 = f2b(rv);
        unsigned v1 = __shfl_down(v0, 1, 64);
        unsigned v2 = __shfl_down(v0, 2, 64);
        unsigned v3 = __shfl_down(v0, 3, 64);
        if ((lane & 3) == 0) {
          u64 pk = (u64)v0 | ((u64)v1 << 16) | ((u64)v2 << 32) | ((u64)v3 << 48);
          st_u64((u64*)(rbuf + blk * (RH * NC) + wv * 64 + lane), pk);
        }
      }
      __syncthreads();                    // drain r stores
      if (tid == 0) st_flag(rflag + blk * 16, (unsigned)(t + 1));
      // gates x/h parts for t+1 (after r publication -- off critical path)
      if (wv < 2 && t < TT - 1) {
        ax0 = f32x4{0.f, 0.f, 0.f, 0.f};
        ax1 = f32x4{0.f, 0.f, 0.f, 0.f};
        x_mfmas(t + 1);
        h_mfmas(t & 1);
      }
    } else {
      // overlap DNC phase C with x-part(t+1); then wait h and do h-part
      if (wv < 2 && t < TT - 1) {
        ax0 = f32x4{0.f, 0.f, 0.f, 0.f};
        ax1 = f32x4{0.f, 0.f, 0.f, 0.f};
        x_mfmas(t + 1);
      }
      wait_h(hflag, (unsigned)(t + 2));
      if (wv < 2 && t < TT - 1) h_mfmas(t & 1);
    }
  }

  // final y(TT-1): needs r(TT-1)
  if (is_y) {
    wait_r(rflag, (unsigned)TT);
    if (wv >= 2) do_y(TT);
  }
}

extern "C" void kernel_launch(void* const* d_in, const int* in_sizes, int n_in,
                              void* d_out, int out_size, void* d_ws, size_t ws_size,
                              hipStream_t stream) {
  const int*   src    = (const int*)d_in[0];
  const float* emb    = (const float*)d_in[2];
  const float* Wih    = (const float*)d_in[3];
  const float* Whh    = (const float*)d_in[4];
  const float* b_lstm = (const float*)d_in[5];
  const float* W_xi   = (const float*)d_in[6];
  const float* b_xi   = (const float*)d_in[7];
  const float* W_out  = (const float*)d_in[8];
  const float* b_out  = (const float*)d_in[9];
  float* out = (float*)d_out;

  char* ws = (char*)d_ws;
  unsigned*       hflag  = (unsigned*)(ws + WS_HFLG);
  unsigned*       rflag  = (unsigned*)(ws + WS_RFLG);
  unsigned short* hbuf   = (unsigned short*)(ws + WS_HBUF);
  unsigned short* rbuf   = (unsigned short*)(ws + WS_RBUF);
  unsigned short* wxbT   = (ws_size >= WS_MIN)  ? (unsigned short*)(ws + WS_WXBT) : nullptr;
  unsigned short* embbuf = (ws_size >= WS_FULL) ? (unsigned short*)(ws + WS_EMB)  : nullptr;

  hipMemsetAsync(d_ws, 0, WS_ZERO, stream);   // flags + h0 + r0
  hipFuncSetAttribute((const void*)dnc_kernel,
                      hipFuncAttributeMaxDynamicSharedMemorySize, SMEM_BYTES);
  dnc_kernel<<<dim3(NBLK), dim3(BS), SMEM_BYTES, stream>>>(
      src, emb, Wih, Whh, b_lstm, W_xi, b_xi, W_out, b_out, out,
      hflag, rflag, hbuf, rbuf, wxbT, embbuf);
}